// Round 1
// baseline (6807.690 us; speedup 1.0000x reference)
//
#include <hip/hip_runtime.h>

// ---------------------------------------------------------------------------
// RNNDecoder: embedding -> 2x LSTM (fused persistent recurrence) -> MHA over
// encoder -> word scatter (mis) -> fc1(tanh) -> fc2 -> log_softmax.
// B=32 L=513 S=1024 H=512 HEADS=4 dh=128 NCLS=128.
// Round 3: minimum-hop recurrence.
//  - Per-layer flag rendezvous (plain sc1 stores, no atomic RMW, no global
//    192-block barrier). L0 (16 blocks) free-runs; L1 (32 blocks) trails.
//  - Weights live in registers (64 bf16x8 frags/lane, loaded once).
//  - Operand-swapped MFMA (W as first operand) => D rows = gate rows,
//    D cols = batch => all 4 gates of 4 consecutive h-cols land in-lane:
//    gates + cell state + 8B store with NO LDS stage on L0's path.
//  - L1: wih1-waves and whh1-waves combine via one 8KB conflict-free LDS
//    exchange, then in-lane gates.
// ---------------------------------------------------------------------------

typedef __attribute__((ext_vector_type(8))) short bf16x8;
typedef __attribute__((ext_vector_type(4))) float f32x4;

union U128 { unsigned long long q[2]; bf16x8 v; };
union HV { ushort4 u; unsigned long long q; };

__device__ __forceinline__ unsigned short f2bf(float f) {
  union { float f; unsigned int u; } v; v.f = f;
  unsigned int r = (v.u + 0x7fffu + ((v.u >> 16) & 1u)) >> 16;
  return (unsigned short)r;
}
__device__ __forceinline__ float bf2f(unsigned short h) {
  union { unsigned int u; float f; } v; v.u = ((unsigned int)h) << 16;
  return v.f;
}

// device-scope (cross-XCD coherent, bypasses stale L1/L2) 8B load/store
__device__ __forceinline__ unsigned long long ld_dev(const unsigned short* p) {
  return __hip_atomic_load((const unsigned long long*)p, __ATOMIC_RELAXED,
                           __HIP_MEMORY_SCOPE_AGENT);
}
__device__ __forceinline__ void st_dev(unsigned short* p, unsigned long long x) {
  __hip_atomic_store((unsigned long long*)p, x, __ATOMIC_RELAXED,
                     __HIP_MEMORY_SCOPE_AGENT);
}
__device__ __forceinline__ unsigned int ld_flag(const unsigned int* p) {
  return __hip_atomic_load(p, __ATOMIC_RELAXED, __HIP_MEMORY_SCOPE_AGENT);
}
__device__ __forceinline__ void st_flag(unsigned int* p, unsigned int v) {
  __hip_atomic_store(p, v, __ATOMIC_RELAXED, __HIP_MEMORY_SCOPE_AGENT);
}

typedef const __attribute__((address_space(1))) void* gp1_t;
typedef __attribute__((address_space(3))) void* lp3_t;
__device__ __forceinline__ void glds16(const void* g, void* s) {
  __builtin_amdgcn_global_load_lds((gp1_t)g, (lp3_t)s, 16, 0, 0);
}

// ---------------------------------------------------------------------------
// Generic bf16 GEMM:  C[m][n] = act( alpha * sum_k A[m][k]*W[n][k] + bias[n] )
// ---------------------------------------------------------------------------
struct Gemm {
  const unsigned short* A; const unsigned short* W; const float* bias;
  float* C1; unsigned short* C2;
  long lda, ldw, ldc1, ldc2;
  long zA, zAh, zW, zWh, zC1, zC1h, zC2, zC2h;
  long M, Mclamp;
  int N, K, heads, act;
  float alpha;
};

__global__ __launch_bounds__(256, 2) void gemm_bt(Gemm g) {
  __shared__ unsigned short aSh[128 * 32];
  __shared__ unsigned short bSh[128 * 32];
  const int tid = threadIdx.x;
  const int wave = tid >> 6, lane = tid & 63;
  const int zb = blockIdx.z / g.heads, zh = blockIdx.z % g.heads;
  const unsigned short* A = g.A + (long)zb * g.zA + (long)zh * g.zAh;
  const unsigned short* W = g.W + (long)zb * g.zW + (long)zh * g.zWh;
  const long mBlk = (long)blockIdx.y * 128;
  const long nBlk = (long)blockIdx.x * 128;
  const int sRow = wave * 16 + (lane >> 2);
  const int sCol = (lane & 3) * 8;
  long ar0 = mBlk + sRow;      if (ar0 > g.Mclamp) ar0 = g.Mclamp;
  long ar1 = mBlk + 64 + sRow; if (ar1 > g.Mclamp) ar1 = g.Mclamp;
  const unsigned short* gA0 = A + ar0 * g.lda + sCol;
  const unsigned short* gA1 = A + ar1 * g.lda + sCol;
  const unsigned short* gW0 = W + (nBlk + sRow) * g.ldw + sCol;
  const unsigned short* gW1 = W + (nBlk + 64 + sRow) * g.ldw + sCol;
  unsigned short* sA0 = aSh + wave * 512;
  unsigned short* sA1 = aSh + 2048 + wave * 512;
  unsigned short* sB0 = bSh + wave * 512;
  unsigned short* sB1 = bSh + 2048 + wave * 512;
  f32x4 acc[4][4] = {};
  const int wm = wave & 1, wn = wave >> 1;
  const int fm = lane & 15, fq = lane >> 4;
  for (int k0 = 0; k0 < g.K; k0 += 32) {
    glds16(gA0 + k0, sA0);
    glds16(gA1 + k0, sA1);
    glds16(gW0 + k0, sB0);
    glds16(gW1 + k0, sB1);
    __syncthreads();
    bf16x8 af[4], bfr[4];
#pragma unroll
    for (int i = 0; i < 4; ++i)
      af[i] = *(const bf16x8*)(aSh + (wm * 64 + i * 16 + fm) * 32 + fq * 8);
#pragma unroll
    for (int j = 0; j < 4; ++j)
      bfr[j] = *(const bf16x8*)(bSh + (wn * 64 + j * 16 + fm) * 32 + fq * 8);
#pragma unroll
    for (int i = 0; i < 4; ++i)
#pragma unroll
      for (int j = 0; j < 4; ++j)
        acc[i][j] = __builtin_amdgcn_mfma_f32_16x16x32_bf16(af[i], bfr[j], acc[i][j], 0, 0, 0);
    __syncthreads();
  }
  float* C1 = g.C1 ? g.C1 + (long)zb * g.zC1 + (long)zh * g.zC1h : nullptr;
  unsigned short* C2 = g.C2 ? g.C2 + (long)zb * g.zC2 + (long)zh * g.zC2h : nullptr;
#pragma unroll
  for (int j = 0; j < 4; ++j) {
    long n = nBlk + wn * 64 + j * 16 + fm;
    float bias = g.bias ? g.bias[n] : 0.f;
#pragma unroll
    for (int i = 0; i < 4; ++i) {
      long mBase = mBlk + wm * 64 + i * 16 + fq * 4;
#pragma unroll
      for (int r = 0; r < 4; ++r) {
        long m = mBase + r;
        if (m < g.M) {
          float v = acc[i][j][r] * g.alpha + bias;
          if (g.act) v = tanhf(v);
          if (C1) C1[m * g.ldc1 + n] = v;
          if (C2) C2[m * g.ldc2 + n] = f2bf(v);
        }
      }
    }
  }
}

// ---------------------------------------------------------------------------
// Fused 2-layer persistent LSTM, 48 blocks:
//   blocks 0..15  : layer 0, 32 h-cols each, weights in registers.
//   blocks 16..47 : layer 1, 16 h-cols each, weights in registers.
// Flags: bar[i*16] (i<16) = L0 block i finished step (value = t+1).
//        bar[(16+j)*16] (j<32) = L1 block j finished step.
// L0 step t waits min(L0 flags) >= t.  L1 step t waits min(L0) >= t+1 and
// min(L1) >= t.  All stores/loads of h are agent-scope (sc1).
// ---------------------------------------------------------------------------
__global__ __launch_bounds__(256, 1) void lstm_fused(
    const float* __restrict__ xp,             // (b*513+t)*2048, bias0 included
    const unsigned short* __restrict__ wih1,  // 2048x512 bf16
    const unsigned short* __restrict__ whh0,  // 2048x512 bf16
    const unsigned short* __restrict__ whh1,  // 2048x512 bf16
    const float* __restrict__ bias1,          // 2048 (b_ih1+b_hh1)
    unsigned short* __restrict__ h0,          // (b*513+t)*512
    unsigned short* __restrict__ h1,          // (b*513+t)*1024 (cat left half)
    unsigned int* bar) {
  __shared__ float xch[16 * 128];             // L1 part-combine, 8 KB
  const int tid = threadIdx.x, lane = tid & 63, wave = tid >> 6;
  const int fm = lane & 15, fq = lane >> 4;
  const int bx = blockIdx.x;

  if (bx < 16) {
    // ----------------------------- layer 0 --------------------------------
    const int j0 = bx * 32;
    const int m = wave & 1, p = wave >> 1;
    const int b = m * 16 + fm;                // batch this lane owns
    const int c0 = p * 16 + fq * 4;           // 4 consecutive h-cols owned
    // register-resident weights: gate g, k-chunk kk -> rows g*32+p*16+fm
    bf16x8 wf[4][16];
#pragma unroll
    for (int g = 0; g < 4; ++g) {
      const unsigned short* wr =
          whh0 + ((long)(g * 512 + j0 + p * 16 + fm)) * 512 + fq * 8;
#pragma unroll
      for (int kk = 0; kk < 16; ++kk)
        wf[g][kk] = *(const bf16x8*)(wr + kk * 32);
    }
    const float* xpt = xp + ((long)b * 513) * 2048 + j0 + c0;
    unsigned short* hout = h0 + ((long)b * 513) * 512 + j0 + c0;
    const unsigned short* hin = h0 + ((long)b * 513) * 512 + fq * 8;
    float cS[4] = {0.f, 0.f, 0.f, 0.f};
#pragma unroll 1
    for (int t = 0; t < 513; ++t) {
      // xp loads issue before the poll -> latency hidden under the spin
      const float4 xi = *(const float4*)(xpt + (long)t * 2048);
      const float4 xf = *(const float4*)(xpt + (long)t * 2048 + 512);
      const float4 xg = *(const float4*)(xpt + (long)t * 2048 + 1024);
      const float4 xo = *(const float4*)(xpt + (long)t * 2048 + 1536);
      if (tid == 0 && t > 0) {
        for (;;) {
          unsigned int mn = ~0u;
#pragma unroll
          for (int i = 0; i < 16; ++i) {
            unsigned int v = ld_flag(bar + i * 16);
            mn = v < mn ? v : mn;
          }
          if (mn >= (unsigned int)t) break;
          __builtin_amdgcn_s_sleep(1);
        }
      }
      __syncthreads();
      f32x4 a0 = {}, a1 = {}, a2 = {}, a3 = {};
      if (t > 0) {
        U128 hf[16];
        const unsigned short* hr = hin + (long)(t - 1) * 512;
#pragma unroll
        for (int kk = 0; kk < 16; ++kk) {
          hf[kk].q[0] = ld_dev(hr + kk * 32);
          hf[kk].q[1] = ld_dev(hr + kk * 32 + 4);
        }
#pragma unroll
        for (int kk = 0; kk < 16; ++kk) {
          a0 = __builtin_amdgcn_mfma_f32_16x16x32_bf16(wf[0][kk], hf[kk].v, a0, 0, 0, 0);
          a1 = __builtin_amdgcn_mfma_f32_16x16x32_bf16(wf[1][kk], hf[kk].v, a1, 0, 0, 0);
          a2 = __builtin_amdgcn_mfma_f32_16x16x32_bf16(wf[2][kk], hf[kk].v, a2, 0, 0, 0);
          a3 = __builtin_amdgcn_mfma_f32_16x16x32_bf16(wf[3][kk], hf[kk].v, a3, 0, 0, 0);
        }
      }
      const float xiv[4] = {xi.x, xi.y, xi.z, xi.w};
      const float xfv[4] = {xf.x, xf.y, xf.z, xf.w};
      const float xgv[4] = {xg.x, xg.y, xg.z, xg.w};
      const float xov[4] = {xo.x, xo.y, xo.z, xo.w};
      unsigned short hh[4];
#pragma unroll
      for (int rr = 0; rr < 4; ++rr) {
        float gi = a0[rr] + xiv[rr];
        float gf = a1[rr] + xfv[rr];
        float gg = a2[rr] + xgv[rr];
        float go = a3[rr] + xov[rr];
        float ig = 1.f / (1.f + __expf(-gi));
        float fg = 1.f / (1.f + __expf(-gf));
        float og = 1.f / (1.f + __expf(-go));
        cS[rr] = fg * cS[rr] + ig * tanhf(gg);
        hh[rr] = f2bf(og * tanhf(cS[rr]));
      }
      HV hv; hv.u.x = hh[0]; hv.u.y = hh[1]; hv.u.z = hh[2]; hv.u.w = hh[3];
      st_dev(hout + (long)t * 512, hv.q);
      __syncthreads();   // drains vmcnt(0): all h stores complete (release)
      if (tid == 0) st_flag(bar + bx * 16, (unsigned int)(t + 1));
    }
  } else {
    // ----------------------------- layer 1 --------------------------------
    const int blk = bx - 16, j0 = blk * 16;
    const int m = wave & 1, part = wave >> 1;  // 0 = wih1(h0[t]), 1 = whh1(h1[t-1])
    const int b = m * 16 + fm;
    const int c0 = fq * 4;
    bf16x8 wf[4][16];
    const unsigned short* wmat = part ? whh1 : wih1;
#pragma unroll
    for (int g = 0; g < 4; ++g) {
      const unsigned short* wr =
          wmat + ((long)(g * 512 + j0 + fm)) * 512 + fq * 8;
#pragma unroll
      for (int kk = 0; kk < 16; ++kk)
        wf[g][kk] = *(const bf16x8*)(wr + kk * 32);
    }
    float bias_r[4][4];
    if (part == 0) {
#pragma unroll
      for (int g = 0; g < 4; ++g) {
        float4 bg = *(const float4*)(bias1 + g * 512 + j0 + c0);
        bias_r[g][0] = bg.x; bias_r[g][1] = bg.y;
        bias_r[g][2] = bg.z; bias_r[g][3] = bg.w;
      }
    }
    const unsigned short* h0in = h0 + ((long)b * 513) * 512 + fq * 8;
    const unsigned short* h1in = h1 + ((long)b * 513) * 1024 + fq * 8;
    unsigned short* hout = h1 + ((long)b * 513) * 1024 + j0 + c0;
    float cS[4] = {0.f, 0.f, 0.f, 0.f};
#pragma unroll 1
    for (int t = 0; t < 513; ++t) {
      if (tid == 0) {
        for (;;) {
          unsigned int mnA = ~0u, mnB = ~0u;
#pragma unroll
          for (int i = 0; i < 16; ++i) {
            unsigned int v = ld_flag(bar + i * 16);
            mnA = v < mnA ? v : mnA;
          }
#pragma unroll
          for (int j = 0; j < 32; ++j) {
            unsigned int v = ld_flag(bar + (16 + j) * 16);
            mnB = v < mnB ? v : mnB;
          }
          if (mnA >= (unsigned int)(t + 1) && mnB >= (unsigned int)t) break;
          __builtin_amdgcn_s_sleep(1);
        }
      }
      __syncthreads();
      f32x4 a0 = {}, a1 = {}, a2 = {}, a3 = {};
      if (part == 0 || t > 0) {
        const unsigned short* hr = (part == 0) ? h0in + (long)t * 512
                                               : h1in + (long)(t - 1) * 1024;
        U128 hf[16];
#pragma unroll
        for (int kk = 0; kk < 16; ++kk) {
          hf[kk].q[0] = ld_dev(hr + kk * 32);
          hf[kk].q[1] = ld_dev(hr + kk * 32 + 4);
        }
#pragma unroll
        for (int kk = 0; kk < 16; ++kk) {
          a0 = __builtin_amdgcn_mfma_f32_16x16x32_bf16(wf[0][kk], hf[kk].v, a0, 0, 0, 0);
          a1 = __builtin_amdgcn_mfma_f32_16x16x32_bf16(wf[1][kk], hf[kk].v, a1, 0, 0, 0);
          a2 = __builtin_amdgcn_mfma_f32_16x16x32_bf16(wf[2][kk], hf[kk].v, a2, 0, 0, 0);
          a3 = __builtin_amdgcn_mfma_f32_16x16x32_bf16(wf[3][kk], hf[kk].v, a3, 0, 0, 0);
        }
      }
      if (part == 1) {
#pragma unroll
        for (int rr = 0; rr < 4; ++rr) {
          xch[(0 * 4 + rr) * 128 + m * 64 + lane] = a0[rr];
          xch[(1 * 4 + rr) * 128 + m * 64 + lane] = a1[rr];
          xch[(2 * 4 + rr) * 128 + m * 64 + lane] = a2[rr];
          xch[(3 * 4 + rr) * 128 + m * 64 + lane] = a3[rr];
        }
      }
      __syncthreads();
      if (part == 0) {
        unsigned short hh[4];
#pragma unroll
        for (int rr = 0; rr < 4; ++rr) {
          float gi = a0[rr] + xch[(0 * 4 + rr) * 128 + m * 64 + lane] + bias_r[0][rr];
          float gf = a1[rr] + xch[(1 * 4 + rr) * 128 + m * 64 + lane] + bias_r[1][rr];
          float gg = a2[rr] + xch[(2 * 4 + rr) * 128 + m * 64 + lane] + bias_r[2][rr];
          float go = a3[rr] + xch[(3 * 4 + rr) * 128 + m * 64 + lane] + bias_r[3][rr];
          float ig = 1.f / (1.f + __expf(-gi));
          float fg = 1.f / (1.f + __expf(-gf));
          float og = 1.f / (1.f + __expf(-go));
          cS[rr] = fg * cS[rr] + ig * tanhf(gg);
          hh[rr] = f2bf(og * tanhf(cS[rr]));
        }
        HV hv; hv.u.x = hh[0]; hv.u.y = hh[1]; hv.u.z = hh[2]; hv.u.w = hh[3];
        st_dev(hout + (long)t * 1024, hv.q);
      }
      __syncthreads();   // drains h1 stores + protects xch reuse
      if (tid == 0) st_flag(bar + (16 + blk) * 16, (unsigned int)(t + 1));
    }
  }
}

// --------------------------- small kernels ---------------------------------

struct CastJob { const float* src; unsigned short* dst; long n; };
struct CastJobs { CastJob j[11]; };
__global__ void cast_multi(CastJobs jb) {
  const CastJob j = jb.j[blockIdx.z];
  long n4 = j.n >> 2;
  for (long i = blockIdx.x * (long)blockDim.x + threadIdx.x; i < n4;
       i += (long)gridDim.x * blockDim.x) {
    float4 f = ((const float4*)j.src)[i];
    ushort4 o;
    o.x = f2bf(f.x); o.y = f2bf(f.y); o.z = f2bf(f.z); o.w = f2bf(f.w);
    ((ushort4*)j.dst)[i] = o;
  }
}

__global__ void bias_sum(const float* a0, const float* b0, float* o0,
                         const float* a1, const float* b1, float* o1) {
  int i = blockIdx.x * 256 + threadIdx.x;
  if (i < 2048) { o0[i] = a0[i] + b0[i]; o1[i] = a1[i] + b1[i]; }
}

__global__ __launch_bounds__(256) void embed_gather(const int* __restrict__ tg,
                                                    const unsigned short* __restrict__ emb,
                                                    unsigned short* __restrict__ out) {
  long row = blockIdx.x;                // 0..16415 = b*513+t
  int id = tg[row];
  const unsigned short* s = emb + (long)id * 512;
  unsigned short* d = out + row * 512;
  int c = threadIdx.x * 2;
  *(ushort2*)(d + c) = *(const ushort2*)(s + c);
}

__global__ void word_map(const int* __restrict__ tg, int* __restrict__ map) {
  int b = threadIdx.x;
  if (b >= 32) return;
  int word_id = 0, start = 0;
  for (int i = 0; i < 512; ++i) {
    int id = tg[b * 513 + i + 1];
    bool bd = (id == 1) || (id == 0);   // SPACE or PAD
    if (bd) {
      map[b * 512 + i] = -1;
      word_id++; start = i + 1;
    } else {
      int pos = i - start; if (pos > 6) pos = 6;
      map[b * 512 + i] = (b * 64 + word_id) * 7 + pos;
    }
  }
}

__global__ __launch_bounds__(256) void vtrans(const unsigned short* __restrict__ v,
                                              unsigned short* __restrict__ vt) {
  __shared__ unsigned short tile[64][33];
  const int bh = blockIdx.z, b = bh >> 2, h = bh & 3;
  const int s0 = blockIdx.x * 64, d0 = blockIdx.y * 32;
  const int tid = threadIdx.x;
  {
    const int dd = tid & 31, sb = tid >> 5;
#pragma unroll
    for (int k = 0; k < 8; ++k) {
      int s = sb + k * 8;
      tile[s][dd] = v[((long)b * 1024 + s0 + s) * 512 + h * 128 + d0 + dd];
    }
  }
  __syncthreads();
  {
    const int ss = tid & 63, db = tid >> 6;
#pragma unroll
    for (int k = 0; k < 8; ++k) {
      int d = db + k * 4;
      vt[((long)bh * 128 + d0 + d) * 1024 + s0 + ss] = tile[ss][d];
    }
  }
}

__global__ __launch_bounds__(256) void softmax_row(unsigned short* __restrict__ sc,
                                                   float* __restrict__ attnOut) {
  const long row = blockIdx.x;          // (b*4+h)*513 + t
  unsigned short* sr = sc + row * 1024;
  const int tid = threadIdx.x, lane = tid & 63, wave = tid >> 6;
  __shared__ float red[8];
  ushort4 raw = *(const ushort4*)(sr + tid * 4);
  float v0 = bf2f(raw.x), v1 = bf2f(raw.y), v2 = bf2f(raw.z), v3 = bf2f(raw.w);
  float m = fmaxf(fmaxf(v0, v1), fmaxf(v2, v3));
  for (int o = 32; o; o >>= 1) m = fmaxf(m, __shfl_down(m, o));
  if (lane == 0) red[wave] = m;
  __syncthreads();
  m = fmaxf(fmaxf(red[0], red[1]), fmaxf(red[2], red[3]));
  float e0 = __expf(v0 - m), e1 = __expf(v1 - m), e2 = __expf(v2 - m), e3 = __expf(v3 - m);
  float s = e0 + e1 + e2 + e3;
  for (int o = 32; o; o >>= 1) s += __shfl_down(s, o);
  if (lane == 0) red[4 + wave] = s;
  __syncthreads();
  float inv = 1.f / (red[4] + red[5] + red[6] + red[7]);
  float a0 = e0 * inv, a1 = e1 * inv, a2 = e2 * inv, a3 = e3 * inv;
  float4 fo; fo.x = a0; fo.y = a1; fo.z = a2; fo.w = a3;
  *(float4*)(attnOut + row * 1024 + tid * 4) = fo;
  ushort4 ob; ob.x = f2bf(a0); ob.y = f2bf(a1); ob.z = f2bf(a2); ob.w = f2bf(a3);
  *(ushort4*)(sr + tid * 4) = ob;       // in-place bf16 attn for ctx GEMM
}

__global__ __launch_bounds__(128) void mis_scatter(const int* __restrict__ map,
                                                   const int* __restrict__ tg,
                                                   const float* __restrict__ emb_w,
                                                   const float* __restrict__ ctx,
                                                   float* __restrict__ mis) {
  int bi = blockIdx.x;                  // b*512 + i
  int g = map[bi];
  if (g < 0) return;
  int b = bi >> 9, i = bi & 511;
  float* dst = mis + (long)g * 1024;
  int id = tg[b * 513 + i + 1];
  const float* es = emb_w + (long)id * 512;
  const float* cs = ctx + ((long)b * 513 + i) * 512;
  for (int c = threadIdx.x; c < 512; c += 128) {
    dst[c] = es[c];
    dst[512 + c] = cs[c];
  }
}

__global__ __launch_bounds__(256) void logsoftmax_rows(const float* __restrict__ logits,
                                                       float* __restrict__ out) {
  int row = blockIdx.x * 4 + (threadIdx.x >> 6);
  if (row >= 16416) return;
  int lane = threadIdx.x & 63;
  const float* lr = logits + (long)row * 128;
  float a = lr[lane], b = lr[lane + 64];
  float m = fmaxf(a, b);
  for (int o = 32; o; o >>= 1) m = fmaxf(m, __shfl_down(m, o));
  m = __shfl(m, 0);
  float s = __expf(a - m) + __expf(b - m);
  for (int o = 32; o; o >>= 1) s += __shfl_down(s, o);
  s = __shfl(s, 0);
  float ls = m + __logf(s);
  out[(long)row * 128 + lane] = a - ls;
  out[(long)row * 128 + lane + 64] = b - ls;
}

// ---------------------------------------------------------------------------

extern "C" void kernel_launch(void* const* d_in, const int* in_sizes, int n_in,
                              void* d_out, int out_size, void* d_ws, size_t ws_size,
                              hipStream_t stream) {
  (void)in_sizes; (void)n_in; (void)out_size; (void)ws_size;
  const int*   targets = (const int*)d_in[0];
  const float* enc   = (const float*)d_in[1];
  const float* emb_w = (const float*)d_in[2];
  const float* w_ih0 = (const float*)d_in[3];
  const float* w_hh0 = (const float*)d_in[4];
  const float* b_ih0 = (const float*)d_in[5];
  const float* b_hh0 = (const float*)d_in[6];
  const float* w_ih1 = (const float*)d_in[7];
  const float* w_hh1 = (const float*)d_in[8];
  const float* b_ih1 = (const float*)d_in[9];
  const float* b_hh1 = (const float*)d_in[10];
  const float* q_w = (const float*)d_in[11]; const float* q_b = (const float*)d_in[12];
  const float* k_w = (const float*)d_in[13]; const float* k_b = (const float*)d_in[14];
  const float* v_w = (const float*)d_in[15]; const float* v_b = (const float*)d_in[16];
  const float* fc1_w = (const float*)d_in[17]; const float* fc1_b = (const float*)d_in[18];
  const float* fc2_w = (const float*)d_in[19]; const float* fc2_b = (const float*)d_in[20];

  float* out_logp = (float*)d_out;
  float* out_attn = out_logp + 2101248;          // (32,4,513,1024)
  float* out_mis  = out_logp + 69341184;         // (2048,7,1024)

  // workspace arena
  char* ws = (char*)d_ws;
  size_t off = 0;
  auto take = [&](size_t bytes) -> char* {
    char* p = ws + off; off += (bytes + 255) & ~(size_t)255; return p;
  };
  unsigned int* bar   = (unsigned int*)take(65536);   // flags, 64B apart
  int* map            = (int*)take(65536);
  float* bias0        = (float*)take(8192);
  float* bias1        = (float*)take(8192);
  unsigned short* wih0b = (unsigned short*)take(2097152);
  unsigned short* whh0b = (unsigned short*)take(2097152);
  unsigned short* wih1b = (unsigned short*)take(2097152);
  unsigned short* whh1b = (unsigned short*)take(2097152);
  unsigned short* qwb   = (unsigned short*)take(524288);
  unsigned short* kwb   = (unsigned short*)take(524288);
  unsigned short* vwb   = (unsigned short*)take(524288);
  unsigned short* fc1wb = (unsigned short*)take(1048576);
  unsigned short* fc2wb = (unsigned short*)take(131072);
  unsigned short* embb  = (unsigned short*)take(131072);
  unsigned short* emb_bf = (unsigned short*)take(16908288);  // (16512x512) bf16
  unsigned short* enc_bf = (unsigned short*)take(33554432);  // (32768x512)
  float* xp             = (float*)take(135266304);           // (16512x2048) f32; aliased by scores
  unsigned short* scores = (unsigned short*)xp;              // (128,513,1024) bf16 alias
  unsigned short* h0_bf = (unsigned short*)take(16908288);   // (16512x512)
  unsigned short* cat_bf = (unsigned short*)take(33816576);  // (16512x1024): [h1 | ctx]
  unsigned short* q_bf  = (unsigned short*)take(16908288);
  unsigned short* k_bf  = (unsigned short*)take(33554432);
  unsigned short* v_bf  = (unsigned short*)take(33554432);
  unsigned short* v_t   = (unsigned short*)take(33554432);   // (128,128,1024)
  float* ctx            = (float*)take(33816576);            // (16512x512)
  unsigned short* h1_bf = (unsigned short*)take(16908288);
  float* logits         = (float*)take(8454144);             // (16512x128)

  hipMemsetAsync(bar, 0, 32768, stream);
  hipMemsetAsync(out_mis, 0, (size_t)14680064 * 4, stream);

  // weight casts
  CastJobs cj;
  cj.j[0]  = {w_ih0, wih0b, 1048576};
  cj.j[1]  = {w_hh0, whh0b, 1048576};
  cj.j[2]  = {w_ih1, wih1b, 1048576};
  cj.j[3]  = {w_hh1, whh1b, 1048576};
  cj.j[4]  = {q_w,   qwb,   262144};
  cj.j[5]  = {k_w,   kwb,   262144};
  cj.j[6]  = {v_w,   vwb,   262144};
  cj.j[7]  = {fc1_w, fc1wb, 524288};
  cj.j[8]  = {fc2_w, fc2wb, 65536};
  cj.j[9]  = {emb_w, embb,  65536};
  cj.j[10] = {enc,   enc_bf, 16777216};
  cast_multi<<<dim3(256, 1, 11), 256, 0, stream>>>(cj);
  bias_sum<<<8, 256, 0, stream>>>(b_ih0, b_hh0, bias0, b_ih1, b_hh1, bias1);
  word_map<<<1, 64, 0, stream>>>(targets, map);
  embed_gather<<<16416, 256, 0, stream>>>(targets, embb, emb_bf);

  auto launch_gemm = [&](const unsigned short* A, long lda, long zA, long zAh,
                         const unsigned short* W, long ldw, long zW, long zWh,
                         const float* bias, float* C1, long ldc1, long zC1, long zC1h,
                         unsigned short* C2, long ldc2, long zC2, long zC2h,
                         long M, long Mclamp, int N, int K, int heads, int Z,
                         float alpha, int act) {
    Gemm g;
    g.A = A; g.W = W; g.bias = bias; g.C1 = C1; g.C2 = C2;
    g.lda = lda; g.ldw = ldw; g.ldc1 = ldc1; g.ldc2 = ldc2;
    g.zA = zA; g.zAh = zAh; g.zW = zW; g.zWh = zWh;
    g.zC1 = zC1; g.zC1h = zC1h; g.zC2 = zC2; g.zC2h = zC2h;
    g.M = M; g.Mclamp = Mclamp; g.N = N; g.K = K; g.heads = heads;
    g.act = act; g.alpha = alpha;
    dim3 grid((unsigned)(N / 128), (unsigned)((M + 127) / 128), (unsigned)Z);
    gemm_bt<<<grid, 256, 0, stream>>>(g);
  };

  // xp0 = embedded @ w_ih0^T + (b_ih0 + b_hh0)
  launch_gemm(emb_bf, 512, 0, 0, wih0b, 512, 0, 0, bias0,
              xp, 2048, 0, 0, nullptr, 0, 0, 0,
              16512, 16511, 2048, 512, 1, 1, 1.f, 0);
  // fused 2-layer recurrence: h0 -> h0_bf, h1 -> cat_bf left half
  lstm_fused<<<48, 256, 0, stream>>>(xp, wih1b, whh0b, whh1b, bias1,
                                     h0_bf, cat_bf, bar);

  // q / k / v projections (bf16 outputs)
  launch_gemm(cat_bf, 1024, 0, 0, qwb, 512, 0, 0, q_b,
              nullptr, 0, 0, 0, q_bf, 512, 0, 0,
              16512, 16511, 512, 512, 1, 1, 1.f, 0);
  launch_gemm(enc_bf, 512, 0, 0, kwb, 512, 0, 0, k_b,
              nullptr, 0, 0, 0, k_bf, 512, 0, 0,
              32768, 32767, 512, 512, 1, 1, 1.f, 0);
  launch_gemm(enc_bf, 512, 0, 0, vwb, 512, 0, 0, v_b,
              nullptr, 0, 0, 0, v_bf, 512, 0, 0,
              32768, 32767, 512, 512, 1, 1, 1.f, 0);
  vtrans<<<dim3(16, 4, 128), 256, 0, stream>>>(v_bf, v_t);

  // scores[b,h,t,s] = (q . k) / sqrt(128)   (bf16, into xp alias)
  launch_gemm(q_bf, 512, 262656, 128, k_bf, 512, 524288, 128, nullptr,
              nullptr, 0, 0, 0, scores, 1024, 2101248, 525312,
              513, 512, 1024, 128, 4, 128, 0.08838834764831845f, 0);
  // softmax rows -> attn f32 out + bf16 in place
  softmax_row<<<65664, 256, 0, stream>>>(scores, out_attn);
  // ctx[b,t,h*128+d] = attn @ v   (f32 ctx + bf16 into cat_bf right half)
  launch_gemm(scores, 1024, 2101248, 525312, v_t, 1024, 524288, 131072, nullptr,
              ctx, 512, 262656, 128, cat_bf + 512, 1024, 525312, 128,
              513, 512, 128, 1024, 4, 128, 1.f, 0);
  // mis scatter (embedded f32 gather + ctx f32)
  mis_scatter<<<16384, 128, 0, stream>>>(map, targets, emb_w, ctx, out_mis);

  // fc1: tanh(cat @ fc1_w^T + b) -> bf16
  launch_gemm(cat_bf, 1024, 0, 0, fc1wb, 1024, 0, 0, fc1_b,
              nullptr, 0, 0, 0, h1_bf, 512, 0, 0,
              16512, 16511, 512, 1024, 1, 1, 1.f, 1);
  // fc2: logits f32
  launch_gemm(h1_bf, 512, 0, 0, fc2wb, 512, 0, 0, fc2_b,
              logits, 128, 0, 0, nullptr, 0, 0, 0,
              16512, 16511, 128, 512, 1, 1, 1.f, 0);
  // log_softmax -> d_out
  logsoftmax_rows<<<4104, 256, 0, stream>>>(logits, out_logp);
}

// Round 2
// 6574.527 us; speedup vs baseline: 1.0355x; 1.0355x over previous
//
#include <hip/hip_runtime.h>

// ---------------------------------------------------------------------------
// RNNDecoder: embedding -> 2x LSTM (fused persistent recurrence) -> MHA over
// encoder -> word scatter (mis) -> fc1(tanh) -> fc2 -> log_softmax.
// B=32 L=513 S=1024 H=512 HEADS=4 dh=128 NCLS=128.
// Round 4: gate-interleaved weight permutation + pinned register weights.
//  - mfma(Wperm, h): perm row r -> (gate r&3, col r>>2) makes lane's acc[rr]
//    = the 4 gates of ONE (batch,col) cell. No LDS, no gate exchange.
//  - Weights loaded once via relaxed atomic loads (not rematerializable).
//    L0: 32 frags/lane (128 VGPR). L1: 32 frags/lane.
//  - Wave-parallel flag polling: lane i loads flag i, shfl_xor min.
//  - L1 two-phase: hh chain (needs L1 flags >= t) overlaps the wait for
//    L0's flag >= t+1; ih chain after.
// ---------------------------------------------------------------------------

typedef __attribute__((ext_vector_type(8))) short bf16x8;
typedef __attribute__((ext_vector_type(4))) float f32x4;

union U128 { unsigned long long q[2]; bf16x8 v; };
union HV { ushort4 u; unsigned long long q; };

__device__ __forceinline__ unsigned short f2bf(float f) {
  union { float f; unsigned int u; } v; v.f = f;
  unsigned int r = (v.u + 0x7fffu + ((v.u >> 16) & 1u)) >> 16;
  return (unsigned short)r;
}
__device__ __forceinline__ float bf2f(unsigned short h) {
  union { unsigned int u; float f; } v; v.u = ((unsigned int)h) << 16;
  return v.f;
}

// agent-scope (cross-XCD coherent, bypasses L1/L2) 8B load/store
__device__ __forceinline__ unsigned long long ld_dev(const unsigned short* p) {
  return __hip_atomic_load((const unsigned long long*)p, __ATOMIC_RELAXED,
                           __HIP_MEMORY_SCOPE_AGENT);
}
__device__ __forceinline__ void st_dev(unsigned short* p, unsigned long long x) {
  __hip_atomic_store((unsigned long long*)p, x, __ATOMIC_RELAXED,
                     __HIP_MEMORY_SCOPE_AGENT);
}
__device__ __forceinline__ unsigned int ld_flag(const unsigned int* p) {
  return __hip_atomic_load(p, __ATOMIC_RELAXED, __HIP_MEMORY_SCOPE_AGENT);
}
__device__ __forceinline__ void st_flag(unsigned int* p, unsigned int v) {
  __hip_atomic_store(p, v, __ATOMIC_RELAXED, __HIP_MEMORY_SCOPE_AGENT);
}

typedef const __attribute__((address_space(1))) void* gp1_t;
typedef __attribute__((address_space(3))) void* lp3_t;
__device__ __forceinline__ void glds16(const void* g, void* s) {
  __builtin_amdgcn_global_load_lds((gp1_t)g, (lp3_t)s, 16, 0, 0);
}

// ---------------------------------------------------------------------------
// Generic bf16 GEMM:  C[m][n] = act( alpha * sum_k A[m][k]*W[n][k] + bias[n] )
// ---------------------------------------------------------------------------
struct Gemm {
  const unsigned short* A; const unsigned short* W; const float* bias;
  float* C1; unsigned short* C2;
  long lda, ldw, ldc1, ldc2;
  long zA, zAh, zW, zWh, zC1, zC1h, zC2, zC2h;
  long M, Mclamp;
  int N, K, heads, act;
  float alpha;
};

__global__ __launch_bounds__(256, 2) void gemm_bt(Gemm g) {
  __shared__ unsigned short aSh[128 * 32];
  __shared__ unsigned short bSh[128 * 32];
  const int tid = threadIdx.x;
  const int wave = tid >> 6, lane = tid & 63;
  const int zb = blockIdx.z / g.heads, zh = blockIdx.z % g.heads;
  const unsigned short* A = g.A + (long)zb * g.zA + (long)zh * g.zAh;
  const unsigned short* W = g.W + (long)zb * g.zW + (long)zh * g.zWh;
  const long mBlk = (long)blockIdx.y * 128;
  const long nBlk = (long)blockIdx.x * 128;
  const int sRow = wave * 16 + (lane >> 2);
  const int sCol = (lane & 3) * 8;
  long ar0 = mBlk + sRow;      if (ar0 > g.Mclamp) ar0 = g.Mclamp;
  long ar1 = mBlk + 64 + sRow; if (ar1 > g.Mclamp) ar1 = g.Mclamp;
  const unsigned short* gA0 = A + ar0 * g.lda + sCol;
  const unsigned short* gA1 = A + ar1 * g.lda + sCol;
  const unsigned short* gW0 = W + (nBlk + sRow) * g.ldw + sCol;
  const unsigned short* gW1 = W + (nBlk + 64 + sRow) * g.ldw + sCol;
  unsigned short* sA0 = aSh + wave * 512;
  unsigned short* sA1 = aSh + 2048 + wave * 512;
  unsigned short* sB0 = bSh + wave * 512;
  unsigned short* sB1 = bSh + 2048 + wave * 512;
  f32x4 acc[4][4] = {};
  const int wm = wave & 1, wn = wave >> 1;
  const int fm = lane & 15, fq = lane >> 4;
  for (int k0 = 0; k0 < g.K; k0 += 32) {
    glds16(gA0 + k0, sA0);
    glds16(gA1 + k0, sA1);
    glds16(gW0 + k0, sB0);
    glds16(gW1 + k0, sB1);
    __syncthreads();
    bf16x8 af[4], bfr[4];
#pragma unroll
    for (int i = 0; i < 4; ++i)
      af[i] = *(const bf16x8*)(aSh + (wm * 64 + i * 16 + fm) * 32 + fq * 8);
#pragma unroll
    for (int j = 0; j < 4; ++j)
      bfr[j] = *(const bf16x8*)(bSh + (wn * 64 + j * 16 + fm) * 32 + fq * 8);
#pragma unroll
    for (int i = 0; i < 4; ++i)
#pragma unroll
      for (int j = 0; j < 4; ++j)
        acc[i][j] = __builtin_amdgcn_mfma_f32_16x16x32_bf16(af[i], bfr[j], acc[i][j], 0, 0, 0);
    __syncthreads();
  }
  float* C1 = g.C1 ? g.C1 + (long)zb * g.zC1 + (long)zh * g.zC1h : nullptr;
  unsigned short* C2 = g.C2 ? g.C2 + (long)zb * g.zC2 + (long)zh * g.zC2h : nullptr;
#pragma unroll
  for (int j = 0; j < 4; ++j) {
    long n = nBlk + wn * 64 + j * 16 + fm;
    float bias = g.bias ? g.bias[n] : 0.f;
#pragma unroll
    for (int i = 0; i < 4; ++i) {
      long mBase = mBlk + wm * 64 + i * 16 + fq * 4;
#pragma unroll
      for (int r = 0; r < 4; ++r) {
        long m = mBase + r;
        if (m < g.M) {
          float v = acc[i][j][r] * g.alpha + bias;
          if (g.act) v = tanhf(v);
          if (C1) C1[m * g.ldc1 + n] = v;
          if (C2) C2[m * g.ldc2 + n] = f2bf(v);
        }
      }
    }
  }
}

// ---------------------------------------------------------------------------
// Fused 2-layer persistent LSTM, 96 blocks:
//   blocks 0..31  : layer 0, 16 h-cols each (2 MFMA tiles / wave)
//   blocks 32..95 : layer 1, 8 h-cols each (1 tile / wave, 2 matrices)
// Flags: bar[i*16] (i<32) = L0 block i done step (value t+1).
//        bar[(32+j)*16] (j<64) = L1 block j done step.
// Weight perm: A-operand row r -> weight row (r&3)*512 + colbase + (r>>2),
// so lane (fm,fq) acc[rr] = gate rr of (batch fm, col colbase+fq).
// ---------------------------------------------------------------------------
__global__ __launch_bounds__(256, 1) void lstm_fused(
    const float* __restrict__ xp,             // (b*513+t)*2048, bias0 included
    const unsigned short* __restrict__ wih1,  // 2048x512 bf16
    const unsigned short* __restrict__ whh0,  // 2048x512 bf16
    const unsigned short* __restrict__ whh1,  // 2048x512 bf16
    const float* __restrict__ bias1,          // 2048 (b_ih1+b_hh1)
    unsigned short* __restrict__ h0,          // (b*513+t)*512
    unsigned short* __restrict__ h1,          // (b*513+t)*1024 (cat left half)
    unsigned int* bar) {
  const int tid = threadIdx.x, lane = tid & 63, wave = tid >> 6;
  const int fm = lane & 15, fq = lane >> 4;
  const int bx = blockIdx.x;
  const int half = wave & 1, cg = wave >> 1;   // cg: col-group selector
  const int b = half * 16 + fm;                // batch this lane's D-col is

  if (bx < 32) {
    // ----------------------------- layer 0 --------------------------------
    const int j0 = bx * 16;
    const int T0 = cg * 2;                     // global tiles T0, T0+1
    // pinned weight frags (atomic loads -> not rematerializable)
    const long wrA = (long)((fm & 3) * 512 + j0 + T0 * 4 + (fm >> 2)) * 512 + fq * 8;
    const long wrB = wrA + 4 * 512;            // tile T0+1: col +4 -> row +4
    U128 wfA[16], wfB[16];
#pragma unroll
    for (int kk = 0; kk < 16; ++kk) {
      wfA[kk].q[0] = ld_dev(whh0 + wrA + kk * 32);
      wfA[kk].q[1] = ld_dev(whh0 + wrA + kk * 32 + 4);
      wfB[kk].q[0] = ld_dev(whh0 + wrB + kk * 32);
      wfB[kk].q[1] = ld_dev(whh0 + wrB + kk * 32 + 4);
    }
    const float* xq = xp + ((long)b * 513) * 2048 + j0 + fq;
    const unsigned short* hin = h0 + ((long)b * 513) * 512 + fq * 8;
    unsigned short* hout = h0 + ((long)b * 513) * 512 + j0;
    float cS0 = 0.f, cS1 = 0.f;
#pragma unroll 1
    for (int t = 0; t < 513; ++t) {
      // xp prefetch (independent of recurrence; completes under the poll)
      const float* xrow = xq + (long)t * 2048;
      float xv0[4], xv1[4];
#pragma unroll
      for (int g = 0; g < 4; ++g) {
        xv0[g] = xrow[g * 512 + T0 * 4];
        xv1[g] = xrow[g * 512 + T0 * 4 + 4];
      }
      f32x4 aE0 = {0.f,0.f,0.f,0.f}, aO0 = {0.f,0.f,0.f,0.f};
      f32x4 aE1 = {0.f,0.f,0.f,0.f}, aO1 = {0.f,0.f,0.f,0.f};
      if (t > 0) {
        if (wave == 0) {
          int mn;
          do {
            int v = (int)ld_flag(bar + (lane & 31) * 16);
#pragma unroll
            for (int o = 32; o; o >>= 1) { int u = __shfl_xor(v, o); v = u < v ? u : v; }
            mn = v;
            if (mn < t) __builtin_amdgcn_s_sleep(1);
          } while (mn < t);
        }
        __syncthreads();
        const unsigned short* hr = hin + (long)(t - 1) * 512;
        U128 hf[16];
#pragma unroll
        for (int kk = 0; kk < 16; ++kk) {
          hf[kk].q[0] = ld_dev(hr + kk * 32);
          hf[kk].q[1] = ld_dev(hr + kk * 32 + 4);
        }
#pragma unroll
        for (int kk = 0; kk < 16; kk += 2) {
          aE0 = __builtin_amdgcn_mfma_f32_16x16x32_bf16(wfA[kk].v, hf[kk].v, aE0, 0, 0, 0);
          aE1 = __builtin_amdgcn_mfma_f32_16x16x32_bf16(wfB[kk].v, hf[kk].v, aE1, 0, 0, 0);
          aO0 = __builtin_amdgcn_mfma_f32_16x16x32_bf16(wfA[kk + 1].v, hf[kk + 1].v, aO0, 0, 0, 0);
          aO1 = __builtin_amdgcn_mfma_f32_16x16x32_bf16(wfB[kk + 1].v, hf[kk + 1].v, aO1, 0, 0, 0);
        }
      }
      // tile 0 gates (all 4 gates in-lane)
      {
        float gi = aE0[0] + aO0[0] + xv0[0];
        float gf = aE0[1] + aO0[1] + xv0[1];
        float gg = aE0[2] + aO0[2] + xv0[2];
        float go = aE0[3] + aO0[3] + xv0[3];
        float ig = 1.f / (1.f + __expf(-gi));
        float fg = 1.f / (1.f + __expf(-gf));
        float og = 1.f / (1.f + __expf(-go));
        cS0 = fg * cS0 + ig * tanhf(gg);
        int hu = f2bf(og * tanhf(cS0));
        int s1 = __shfl(hu, fm + 16), s2 = __shfl(hu, fm + 32), s3 = __shfl(hu, fm + 48);
        if (fq == 0) {
          HV hv; hv.u.x = (unsigned short)hu; hv.u.y = (unsigned short)s1;
          hv.u.z = (unsigned short)s2; hv.u.w = (unsigned short)s3;
          st_dev(hout + (long)t * 512 + T0 * 4, hv.q);
        }
      }
      // tile 1 gates
      {
        float gi = aE1[0] + aO1[0] + xv1[0];
        float gf = aE1[1] + aO1[1] + xv1[1];
        float gg = aE1[2] + aO1[2] + xv1[2];
        float go = aE1[3] + aO1[3] + xv1[3];
        float ig = 1.f / (1.f + __expf(-gi));
        float fg = 1.f / (1.f + __expf(-gf));
        float og = 1.f / (1.f + __expf(-go));
        cS1 = fg * cS1 + ig * tanhf(gg);
        int hu = f2bf(og * tanhf(cS1));
        int s1 = __shfl(hu, fm + 16), s2 = __shfl(hu, fm + 32), s3 = __shfl(hu, fm + 48);
        if (fq == 0) {
          HV hv; hv.u.x = (unsigned short)hu; hv.u.y = (unsigned short)s1;
          hv.u.z = (unsigned short)s2; hv.u.w = (unsigned short)s3;
          st_dev(hout + (long)t * 512 + T0 * 4 + 4, hv.q);
        }
      }
      __syncthreads();   // drains vmcnt: all h stores at coherence point
      if (tid == 0) st_flag(bar + bx * 16, (unsigned int)(t + 1));
    }
  } else {
    // ----------------------------- layer 1 --------------------------------
    const int blk = bx - 32, j0 = blk * 8;
    const int col = j0 + cg * 4 + fq;          // this lane's owned column
    const long wr = (long)((fm & 3) * 512 + j0 + cg * 4 + (fm >> 2)) * 512 + fq * 8;
    U128 wfi[16], wfh[16];
#pragma unroll
    for (int kk = 0; kk < 16; ++kk) {
      wfi[kk].q[0] = ld_dev(wih1 + wr + kk * 32);
      wfi[kk].q[1] = ld_dev(wih1 + wr + kk * 32 + 4);
      wfh[kk].q[0] = ld_dev(whh1 + wr + kk * 32);
      wfh[kk].q[1] = ld_dev(whh1 + wr + kk * 32 + 4);
    }
    const float bv0 = bias1[col];
    const float bv1 = bias1[512 + col];
    const float bv2 = bias1[1024 + col];
    const float bv3 = bias1[1536 + col];
    const unsigned short* h0in = h0 + ((long)b * 513) * 512 + fq * 8;
    const unsigned short* h1in = h1 + ((long)b * 513) * 1024 + fq * 8;
    unsigned short* hout = h1 + ((long)b * 513) * 1024 + j0 + cg * 4;
    float cS = 0.f;
#pragma unroll 1
    for (int t = 0; t < 513; ++t) {
      // ---- phase A: hh chain (needs L1 flags >= t) ----
      f32x4 aHE = {0.f,0.f,0.f,0.f}, aHO = {0.f,0.f,0.f,0.f};
      if (t > 0) {
        if (wave == 0) {
          int mn;
          do {
            int v = (int)ld_flag(bar + (32 + lane) * 16);
#pragma unroll
            for (int o = 32; o; o >>= 1) { int u = __shfl_xor(v, o); v = u < v ? u : v; }
            mn = v;
            if (mn < t) __builtin_amdgcn_s_sleep(1);
          } while (mn < t);
        }
        __syncthreads();
        const unsigned short* hr = h1in + (long)(t - 1) * 1024;
        U128 hf[16];
#pragma unroll
        for (int kk = 0; kk < 16; ++kk) {
          hf[kk].q[0] = ld_dev(hr + kk * 32);
          hf[kk].q[1] = ld_dev(hr + kk * 32 + 4);
        }
#pragma unroll
        for (int kk = 0; kk < 16; kk += 2) {
          aHE = __builtin_amdgcn_mfma_f32_16x16x32_bf16(wfh[kk].v, hf[kk].v, aHE, 0, 0, 0);
          aHO = __builtin_amdgcn_mfma_f32_16x16x32_bf16(wfh[kk + 1].v, hf[kk + 1].v, aHO, 0, 0, 0);
        }
      }
      // ---- phase B: ih chain (needs L0 flags >= t+1) ----
      if (wave == 0) {
        int mn;
        do {
          int v = (int)ld_flag(bar + (lane & 31) * 16);
#pragma unroll
          for (int o = 32; o; o >>= 1) { int u = __shfl_xor(v, o); v = u < v ? u : v; }
          mn = v;
          if (mn < t + 1) __builtin_amdgcn_s_sleep(1);
        } while (mn < t + 1);
      }
      __syncthreads();
      f32x4 aIE = {0.f,0.f,0.f,0.f}, aIO = {0.f,0.f,0.f,0.f};
      {
        const unsigned short* hr = h0in + (long)t * 512;
        U128 hf[16];
#pragma unroll
        for (int kk = 0; kk < 16; ++kk) {
          hf[kk].q[0] = ld_dev(hr + kk * 32);
          hf[kk].q[1] = ld_dev(hr + kk * 32 + 4);
        }
#pragma unroll
        for (int kk = 0; kk < 16; kk += 2) {
          aIE = __builtin_amdgcn_mfma_f32_16x16x32_bf16(wfi[kk].v, hf[kk].v, aIE, 0, 0, 0);
          aIO = __builtin_amdgcn_mfma_f32_16x16x32_bf16(wfi[kk + 1].v, hf[kk + 1].v, aIO, 0, 0, 0);
        }
      }
      {
        float gi = aIE[0] + aIO[0] + aHE[0] + aHO[0] + bv0;
        float gf = aIE[1] + aIO[1] + aHE[1] + aHO[1] + bv1;
        float gg = aIE[2] + aIO[2] + aHE[2] + aHO[2] + bv2;
        float go = aIE[3] + aIO[3] + aHE[3] + aHO[3] + bv3;
        float ig = 1.f / (1.f + __expf(-gi));
        float fg = 1.f / (1.f + __expf(-gf));
        float og = 1.f / (1.f + __expf(-go));
        cS = fg * cS + ig * tanhf(gg);
        int hu = f2bf(og * tanhf(cS));
        int s1 = __shfl(hu, fm + 16), s2 = __shfl(hu, fm + 32), s3 = __shfl(hu, fm + 48);
        if (fq == 0) {
          HV hv; hv.u.x = (unsigned short)hu; hv.u.y = (unsigned short)s1;
          hv.u.z = (unsigned short)s2; hv.u.w = (unsigned short)s3;
          st_dev(hout + (long)t * 1024, hv.q);
        }
      }
      __syncthreads();   // drains h1 stores
      if (tid == 0) st_flag(bar + (32 + blk) * 16, (unsigned int)(t + 1));
    }
  }
}

// --------------------------- small kernels ---------------------------------

struct CastJob { const float* src; unsigned short* dst; long n; };
struct CastJobs { CastJob j[11]; };
__global__ void cast_multi(CastJobs jb) {
  const CastJob j = jb.j[blockIdx.z];
  long n4 = j.n >> 2;
  for (long i = blockIdx.x * (long)blockDim.x + threadIdx.x; i < n4;
       i += (long)gridDim.x * blockDim.x) {
    float4 f = ((const float4*)j.src)[i];
    ushort4 o;
    o.x = f2bf(f.x); o.y = f2bf(f.y); o.z = f2bf(f.z); o.w = f2bf(f.w);
    ((ushort4*)j.dst)[i] = o;
  }
}

__global__ void bias_sum(const float* a0, const float* b0, float* o0,
                         const float* a1, const float* b1, float* o1) {
  int i = blockIdx.x * 256 + threadIdx.x;
  if (i < 2048) { o0[i] = a0[i] + b0[i]; o1[i] = a1[i] + b1[i]; }
}

__global__ __launch_bounds__(256) void embed_gather(const int* __restrict__ tg,
                                                    const unsigned short* __restrict__ emb,
                                                    unsigned short* __restrict__ out) {
  long row = blockIdx.x;                // 0..16415 = b*513+t
  int id = tg[row];
  const unsigned short* s = emb + (long)id * 512;
  unsigned short* d = out + row * 512;
  int c = threadIdx.x * 2;
  *(ushort2*)(d + c) = *(const ushort2*)(s + c);
}

__global__ void word_map(const int* __restrict__ tg, int* __restrict__ map) {
  int b = threadIdx.x;
  if (b >= 32) return;
  int word_id = 0, start = 0;
  for (int i = 0; i < 512; ++i) {
    int id = tg[b * 513 + i + 1];
    bool bd = (id == 1) || (id == 0);   // SPACE or PAD
    if (bd) {
      map[b * 512 + i] = -1;
      word_id++; start = i + 1;
    } else {
      int pos = i - start; if (pos > 6) pos = 6;
      map[b * 512 + i] = (b * 64 + word_id) * 7 + pos;
    }
  }
}

__global__ __launch_bounds__(256) void vtrans(const unsigned short* __restrict__ v,
                                              unsigned short* __restrict__ vt) {
  __shared__ unsigned short tile[64][33];
  const int bh = blockIdx.z, b = bh >> 2, h = bh & 3;
  const int s0 = blockIdx.x * 64, d0 = blockIdx.y * 32;
  const int tid = threadIdx.x;
  {
    const int dd = tid & 31, sb = tid >> 5;
#pragma unroll
    for (int k = 0; k < 8; ++k) {
      int s = sb + k * 8;
      tile[s][dd] = v[((long)b * 1024 + s0 + s) * 512 + h * 128 + d0 + dd];
    }
  }
  __syncthreads();
  {
    const int ss = tid & 63, db = tid >> 6;
#pragma unroll
    for (int k = 0; k < 8; ++k) {
      int d = db + k * 4;
      vt[((long)bh * 128 + d0 + d) * 1024 + s0 + ss] = tile[ss][d];
    }
  }
}

__global__ __launch_bounds__(256) void softmax_row(unsigned short* __restrict__ sc,
                                                   float* __restrict__ attnOut) {
  const long row = blockIdx.x;          // (b*4+h)*513 + t
  unsigned short* sr = sc + row * 1024;
  const int tid = threadIdx.x, lane = tid & 63, wave = tid >> 6;
  __shared__ float red[8];
  ushort4 raw = *(const ushort4*)(sr + tid * 4);
  float v0 = bf2f(raw.x), v1 = bf2f(raw.y), v2 = bf2f(raw.z), v3 = bf2f(raw.w);
  float m = fmaxf(fmaxf(v0, v1), fmaxf(v2, v3));
  for (int o = 32; o; o >>= 1) m = fmaxf(m, __shfl_down(m, o));
  if (lane == 0) red[wave] = m;
  __syncthreads();
  m = fmaxf(fmaxf(red[0], red[1]), fmaxf(red[2], red[3]));
  float e0 = __expf(v0 - m), e1 = __expf(v1 - m), e2 = __expf(v2 - m), e3 = __expf(v3 - m);
  float s = e0 + e1 + e2 + e3;
  for (int o = 32; o; o >>= 1) s += __shfl_down(s, o);
  if (lane == 0) red[4 + wave] = s;
  __syncthreads();
  float inv = 1.f / (red[4] + red[5] + red[6] + red[7]);
  float a0 = e0 * inv, a1 = e1 * inv, a2 = e2 * inv, a3 = e3 * inv;
  float4 fo; fo.x = a0; fo.y = a1; fo.z = a2; fo.w = a3;
  *(float4*)(attnOut + row * 1024 + tid * 4) = fo;
  ushort4 ob; ob.x = f2bf(a0); ob.y = f2bf(a1); ob.z = f2bf(a2); ob.w = f2bf(a3);
  *(ushort4*)(sr + tid * 4) = ob;       // in-place bf16 attn for ctx GEMM
}

__global__ __launch_bounds__(128) void mis_scatter(const int* __restrict__ map,
                                                   const int* __restrict__ tg,
                                                   const float* __restrict__ emb_w,
                                                   const float* __restrict__ ctx,
                                                   float* __restrict__ mis) {
  int bi = blockIdx.x;                  // b*512 + i
  int g = map[bi];
  if (g < 0) return;
  int b = bi >> 9, i = bi & 511;
  float* dst = mis + (long)g * 1024;
  int id = tg[b * 513 + i + 1];
  const float* es = emb_w + (long)id * 512;
  const float* cs = ctx + ((long)b * 513 + i) * 512;
  for (int c = threadIdx.x; c < 512; c += 128) {
    dst[c] = es[c];
    dst[512 + c] = cs[c];
  }
}

__global__ __launch_bounds__(256) void logsoftmax_rows(const float* __restrict__ logits,
                                                       float* __restrict__ out) {
  int row = blockIdx.x * 4 + (threadIdx.x >> 6);
  if (row >= 16416) return;
  int lane = threadIdx.x & 63;
  const float* lr = logits + (long)row * 128;
  float a = lr[lane], b = lr[lane + 64];
  float m = fmaxf(a, b);
  for (int o = 32; o; o >>= 1) m = fmaxf(m, __shfl_down(m, o));
  m = __shfl(m, 0);
  float s = __expf(a - m) + __expf(b - m);
  for (int o = 32; o; o >>= 1) s += __shfl_down(s, o);
  s = __shfl(s, 0);
  float ls = m + __logf(s);
  out[(long)row * 128 + lane] = a - ls;
  out[(long)row * 128 + lane + 64] = b - ls;
}

// ---------------------------------------------------------------------------

extern "C" void kernel_launch(void* const* d_in, const int* in_sizes, int n_in,
                              void* d_out, int out_size, void* d_ws, size_t ws_size,
                              hipStream_t stream) {
  (void)in_sizes; (void)n_in; (void)out_size; (void)ws_size;
  const int*   targets = (const int*)d_in[0];
  const float* enc   = (const float*)d_in[1];
  const float* emb_w = (const float*)d_in[2];
  const float* w_ih0 = (const float*)d_in[3];
  const float* w_hh0 = (const float*)d_in[4];
  const float* b_ih0 = (const float*)d_in[5];
  const float* b_hh0 = (const float*)d_in[6];
  const float* w_ih1 = (const float*)d_in[7];
  const float* w_hh1 = (const float*)d_in[8];
  const float* b_ih1 = (const float*)d_in[9];
  const float* b_hh1 = (const float*)d_in[10];
  const float* q_w = (const float*)d_in[11]; const float* q_b = (const float*)d_in[12];
  const float* k_w = (const float*)d_in[13]; const float* k_b = (const float*)d_in[14];
  const float* v_w = (const float*)d_in[15]; const float* v_b = (const float*)d_in[16];
  const float* fc1_w = (const float*)d_in[17]; const float* fc1_b = (const float*)d_in[18];
  const float* fc2_w = (const float*)d_in[19]; const float* fc2_b = (const float*)d_in[20];

  float* out_logp = (float*)d_out;
  float* out_attn = out_logp + 2101248;          // (32,4,513,1024)
  float* out_mis  = out_logp + 69341184;         // (2048,7,1024)

  // workspace arena
  char* ws = (char*)d_ws;
  size_t off = 0;
  auto take = [&](size_t bytes) -> char* {
    char* p = ws + off; off += (bytes + 255) & ~(size_t)255; return p;
  };
  unsigned int* bar   = (unsigned int*)take(65536);   // flags, 64B apart
  int* map            = (int*)take(65536);
  float* bias0        = (float*)take(8192);
  float* bias1        = (float*)take(8192);
  unsigned short* wih0b = (unsigned short*)take(2097152);
  unsigned short* whh0b = (unsigned short*)take(2097152);
  unsigned short* wih1b = (unsigned short*)take(2097152);
  unsigned short* whh1b = (unsigned short*)take(2097152);
  unsigned short* qwb   = (unsigned short*)take(524288);
  unsigned short* kwb   = (unsigned short*)take(524288);
  unsigned short* vwb   = (unsigned short*)take(524288);
  unsigned short* fc1wb = (unsigned short*)take(1048576);
  unsigned short* fc2wb = (unsigned short*)take(131072);
  unsigned short* embb  = (unsigned short*)take(131072);
  unsigned short* emb_bf = (unsigned short*)take(16908288);  // (16512x512) bf16
  unsigned short* enc_bf = (unsigned short*)take(33554432);  // (32768x512)
  float* xp             = (float*)take(135266304);           // (16512x2048) f32; aliased by scores
  unsigned short* scores = (unsigned short*)xp;              // (128,513,1024) bf16 alias
  unsigned short* h0_bf = (unsigned short*)take(16908288);   // (16512x512)
  unsigned short* cat_bf = (unsigned short*)take(33816576);  // (16512x1024): [h1 | ctx]
  unsigned short* q_bf  = (unsigned short*)take(16908288);
  unsigned short* k_bf  = (unsigned short*)take(33554432);
  unsigned short* v_bf  = (unsigned short*)take(33554432);
  unsigned short* v_t   = (unsigned short*)take(33554432);   // (128,128,1024)
  float* ctx            = (float*)take(33816576);            // (16512x512)
  unsigned short* h1_bf = (unsigned short*)take(16908288);
  float* logits         = (float*)take(8454144);             // (16512x128)

  hipMemsetAsync(bar, 0, 32768, stream);
  hipMemsetAsync(out_mis, 0, (size_t)14680064 * 4, stream);

  // weight casts
  CastJobs cj;
  cj.j[0]  = {w_ih0, wih0b, 1048576};
  cj.j[1]  = {w_hh0, whh0b, 1048576};
  cj.j[2]  = {w_ih1, wih1b, 1048576};
  cj.j[3]  = {w_hh1, whh1b, 1048576};
  cj.j[4]  = {q_w,   qwb,   262144};
  cj.j[5]  = {k_w,   kwb,   262144};
  cj.j[6]  = {v_w,   vwb,   262144};
  cj.j[7]  = {fc1_w, fc1wb, 524288};
  cj.j[8]  = {fc2_w, fc2wb, 65536};
  cj.j[9]  = {emb_w, embb,  65536};
  cj.j[10] = {enc,   enc_bf, 16777216};
  cast_multi<<<dim3(256, 1, 11), 256, 0, stream>>>(cj);
  bias_sum<<<8, 256, 0, stream>>>(b_ih0, b_hh0, bias0, b_ih1, b_hh1, bias1);
  word_map<<<1, 64, 0, stream>>>(targets, map);
  embed_gather<<<16416, 256, 0, stream>>>(targets, embb, emb_bf);

  auto launch_gemm = [&](const unsigned short* A, long lda, long zA, long zAh,
                         const unsigned short* W, long ldw, long zW, long zWh,
                         const float* bias, float* C1, long ldc1, long zC1, long zC1h,
                         unsigned short* C2, long ldc2, long zC2, long zC2h,
                         long M, long Mclamp, int N, int K, int heads, int Z,
                         float alpha, int act) {
    Gemm g;
    g.A = A; g.W = W; g.bias = bias; g.C1 = C1; g.C2 = C2;
    g.lda = lda; g.ldw = ldw; g.ldc1 = ldc1; g.ldc2 = ldc2;
    g.zA = zA; g.zAh = zAh; g.zW = zW; g.zWh = zWh;
    g.zC1 = zC1; g.zC1h = zC1h; g.zC2 = zC2; g.zC2h = zC2h;
    g.M = M; g.Mclamp = Mclamp; g.N = N; g.K = K; g.heads = heads;
    g.act = act; g.alpha = alpha;
    dim3 grid((unsigned)(N / 128), (unsigned)((M + 127) / 128), (unsigned)Z);
    gemm_bt<<<grid, 256, 0, stream>>>(g);
  };

  // xp0 = embedded @ w_ih0^T + (b_ih0 + b_hh0)
  launch_gemm(emb_bf, 512, 0, 0, wih0b, 512, 0, 0, bias0,
              xp, 2048, 0, 0, nullptr, 0, 0, 0,
              16512, 16511, 2048, 512, 1, 1, 1.f, 0);
  // fused 2-layer recurrence: h0 -> h0_bf, h1 -> cat_bf left half
  lstm_fused<<<96, 256, 0, stream>>>(xp, wih1b, whh0b, whh1b, bias1,
                                     h0_bf, cat_bf, bar);

  // q / k / v projections (bf16 outputs)
  launch_gemm(cat_bf, 1024, 0, 0, qwb, 512, 0, 0, q_b,
              nullptr, 0, 0, 0, q_bf, 512, 0, 0,
              16512, 16511, 512, 512, 1, 1, 1.f, 0);
  launch_gemm(enc_bf, 512, 0, 0, kwb, 512, 0, 0, k_b,
              nullptr, 0, 0, 0, k_bf, 512, 0, 0,
              32768, 32767, 512, 512, 1, 1, 1.f, 0);
  launch_gemm(enc_bf, 512, 0, 0, vwb, 512, 0, 0, v_b,
              nullptr, 0, 0, 0, v_bf, 512, 0, 0,
              32768, 32767, 512, 512, 1, 1, 1.f, 0);
  vtrans<<<dim3(16, 4, 128), 256, 0, stream>>>(v_bf, v_t);

  // scores[b,h,t,s] = (q . k) / sqrt(128)   (bf16, into xp alias)
  launch_gemm(q_bf, 512, 262656, 128, k_bf, 512, 524288, 128, nullptr,
              nullptr, 0, 0, 0, scores, 1024, 2101248, 525312,
              513, 512, 1024, 128, 4, 128, 0.08838834764831845f, 0);
  // softmax rows -> attn f32 out + bf16 in place
  softmax_row<<<65664, 256, 0, stream>>>(scores, out_attn);
  // ctx[b,t,h*128+d] = attn @ v   (f32 ctx + bf16 into cat_bf right half)
  launch_gemm(scores, 1024, 2101248, 525312, v_t, 1024, 524288, 131072, nullptr,
              ctx, 512, 262656, 128, cat_bf + 512, 1024, 525312, 128,
              513, 512, 128, 1024, 4, 128, 1.f, 0);
  // mis scatter (embedded f32 gather + ctx f32)
  mis_scatter<<<16384, 128, 0, stream>>>(map, targets, emb_w, ctx, out_mis);

  // fc1: tanh(cat @ fc1_w^T + b) -> bf16
  launch_gemm(cat_bf, 1024, 0, 0, fc1wb, 1024, 0, 0, fc1_b,
              nullptr, 0, 0, 0, h1_bf, 512, 0, 0,
              16512, 16511, 512, 1024, 1, 1, 1.f, 1);
  // fc2: logits f32
  launch_gemm(h1_bf, 512, 0, 0, fc2wb, 512, 0, 0, fc2_b,
              logits, 128, 0, 0, nullptr, 0, 0, 0,
              16512, 16511, 128, 512, 1, 1, 1.f, 0);
  // log_softmax -> d_out
  logsoftmax_rows<<<4104, 256, 0, stream>>>(logits, out_logp);
}

// Round 3
// 4157.655 us; speedup vs baseline: 1.6374x; 1.5813x over previous
//
#include <hip/hip_runtime.h>

// ---------------------------------------------------------------------------
// RNNDecoder: embedding -> 2x LSTM (fused persistent recurrence) -> MHA over
// encoder -> word scatter (mis) -> fc1(tanh) -> fc2 -> log_softmax.
// B=32 L=513 S=1024 H=512 HEADS=4 dh=128 NCLS=128.
// Round 5: round-0 compute structure (LDS weights, gS exchange, VGPR 52),
// with the rendezvous replaced:
//  - per-block monotonic flag words (plain sc1 stores, no atomic RMW)
//  - wave-parallel flag polling (lane i loads flag i, shfl_xor min)
//  - layer-decoupled waits: L0 waits only on L0 flags (free-runs);
//    L1 waits min(L0) >= t+1 && min(L1) >= t  ==  min(L0, L1+1) >= t+1.
// ---------------------------------------------------------------------------

typedef __attribute__((ext_vector_type(8))) short bf16x8;
typedef __attribute__((ext_vector_type(4))) float f32x4;

union U128 { unsigned long long q[2]; bf16x8 v; };

__device__ __forceinline__ unsigned short f2bf(float f) {
  union { float f; unsigned int u; } v; v.f = f;
  unsigned int r = (v.u + 0x7fffu + ((v.u >> 16) & 1u)) >> 16;
  return (unsigned short)r;
}
__device__ __forceinline__ float bf2f(unsigned short h) {
  union { unsigned int u; float f; } v; v.u = ((unsigned int)h) << 16;
  return v.f;
}

// agent-scope (cross-XCD coherent, bypasses stale L1/L2) 8B load/store
__device__ __forceinline__ unsigned long long ld_dev(const unsigned short* p) {
  return __hip_atomic_load((const unsigned long long*)p, __ATOMIC_RELAXED,
                           __HIP_MEMORY_SCOPE_AGENT);
}
__device__ __forceinline__ void st_dev(unsigned short* p, unsigned long long x) {
  __hip_atomic_store((unsigned long long*)p, x, __ATOMIC_RELAXED,
                     __HIP_MEMORY_SCOPE_AGENT);
}
__device__ __forceinline__ unsigned int ld_flag(const unsigned int* p) {
  return __hip_atomic_load(p, __ATOMIC_RELAXED, __HIP_MEMORY_SCOPE_AGENT);
}
__device__ __forceinline__ void st_flag(unsigned int* p, unsigned int v) {
  __hip_atomic_store(p, v, __ATOMIC_RELAXED, __HIP_MEMORY_SCOPE_AGENT);
}

typedef const __attribute__((address_space(1))) void* gp1_t;
typedef __attribute__((address_space(3))) void* lp3_t;
__device__ __forceinline__ void glds16(const void* g, void* s) {
  __builtin_amdgcn_global_load_lds((gp1_t)g, (lp3_t)s, 16, 0, 0);
}

// ---------------------------------------------------------------------------
// Generic bf16 GEMM:  C[m][n] = act( alpha * sum_k A[m][k]*W[n][k] + bias[n] )
// ---------------------------------------------------------------------------
struct Gemm {
  const unsigned short* A; const unsigned short* W; const float* bias;
  float* C1; unsigned short* C2;
  long lda, ldw, ldc1, ldc2;
  long zA, zAh, zW, zWh, zC1, zC1h, zC2, zC2h;
  long M, Mclamp;
  int N, K, heads, act;
  float alpha;
};

__global__ __launch_bounds__(256, 2) void gemm_bt(Gemm g) {
  __shared__ unsigned short aSh[128 * 32];
  __shared__ unsigned short bSh[128 * 32];
  const int tid = threadIdx.x;
  const int wave = tid >> 6, lane = tid & 63;
  const int zb = blockIdx.z / g.heads, zh = blockIdx.z % g.heads;
  const unsigned short* A = g.A + (long)zb * g.zA + (long)zh * g.zAh;
  const unsigned short* W = g.W + (long)zb * g.zW + (long)zh * g.zWh;
  const long mBlk = (long)blockIdx.y * 128;
  const long nBlk = (long)blockIdx.x * 128;
  const int sRow = wave * 16 + (lane >> 2);
  const int sCol = (lane & 3) * 8;
  long ar0 = mBlk + sRow;      if (ar0 > g.Mclamp) ar0 = g.Mclamp;
  long ar1 = mBlk + 64 + sRow; if (ar1 > g.Mclamp) ar1 = g.Mclamp;
  const unsigned short* gA0 = A + ar0 * g.lda + sCol;
  const unsigned short* gA1 = A + ar1 * g.lda + sCol;
  const unsigned short* gW0 = W + (nBlk + sRow) * g.ldw + sCol;
  const unsigned short* gW1 = W + (nBlk + 64 + sRow) * g.ldw + sCol;
  unsigned short* sA0 = aSh + wave * 512;
  unsigned short* sA1 = aSh + 2048 + wave * 512;
  unsigned short* sB0 = bSh + wave * 512;
  unsigned short* sB1 = bSh + 2048 + wave * 512;
  f32x4 acc[4][4] = {};
  const int wm = wave & 1, wn = wave >> 1;
  const int fm = lane & 15, fq = lane >> 4;
  for (int k0 = 0; k0 < g.K; k0 += 32) {
    glds16(gA0 + k0, sA0);
    glds16(gA1 + k0, sA1);
    glds16(gW0 + k0, sB0);
    glds16(gW1 + k0, sB1);
    __syncthreads();
    bf16x8 af[4], bfr[4];
#pragma unroll
    for (int i = 0; i < 4; ++i)
      af[i] = *(const bf16x8*)(aSh + (wm * 64 + i * 16 + fm) * 32 + fq * 8);
#pragma unroll
    for (int j = 0; j < 4; ++j)
      bfr[j] = *(const bf16x8*)(bSh + (wn * 64 + j * 16 + fm) * 32 + fq * 8);
#pragma unroll
    for (int i = 0; i < 4; ++i)
#pragma unroll
      for (int j = 0; j < 4; ++j)
        acc[i][j] = __builtin_amdgcn_mfma_f32_16x16x32_bf16(af[i], bfr[j], acc[i][j], 0, 0, 0);
    __syncthreads();
  }
  float* C1 = g.C1 ? g.C1 + (long)zb * g.zC1 + (long)zh * g.zC1h : nullptr;
  unsigned short* C2 = g.C2 ? g.C2 + (long)zb * g.zC2 + (long)zh * g.zC2h : nullptr;
#pragma unroll
  for (int j = 0; j < 4; ++j) {
    long n = nBlk + wn * 64 + j * 16 + fm;
    float bias = g.bias ? g.bias[n] : 0.f;
#pragma unroll
    for (int i = 0; i < 4; ++i) {
      long mBase = mBlk + wm * 64 + i * 16 + fq * 4;
#pragma unroll
      for (int r = 0; r < 4; ++r) {
        long m = mBase + r;
        if (m < g.M) {
          float v = acc[i][j][r] * g.alpha + bias;
          if (g.act) v = tanhf(v);
          if (C1) C1[m * g.ldc1 + n] = v;
          if (C2) C2[m * g.ldc2 + n] = f2bf(v);
        }
      }
    }
  }
}

// ---------------------------------------------------------------------------
// Fused 2-layer persistent LSTM. 192 blocks:
//   blocks 0..63   : layer 0, 8 h-cols each (w_hh0 slice 32x512 in LDS)
//   blocks 64..191 : layer 1, 4 h-cols each (w_ih1 + w_hh1 slices in LDS)
// Flags: bar[bx*16] = block bx finished step (monotonic value = t+1).
// L0 step t waits min(L0 flags) >= t.   L1 step t waits min(L0) >= t+1 and
// min(L1) >= t, folded as min(L0, L1+1) >= t+1.  Flag stored after the
// vmcnt-draining __syncthreads, so h stores are at the coherence point first.
// ---------------------------------------------------------------------------
__global__ __launch_bounds__(256, 1) void lstm_fused(
    const float* __restrict__ xp,             // (b*513+t)*2048, bias0 included
    const unsigned short* __restrict__ wih1,  // 2048x512
    const unsigned short* __restrict__ whh0,  // 2048x512
    const unsigned short* __restrict__ whh1,  // 2048x512
    const float* __restrict__ bias1,          // 2048 (b_ih1+b_hh1)
    unsigned short* __restrict__ h0,          // (b*513+t)*512
    unsigned short* __restrict__ h1,          // (b*513+t)*1024 (cat left half)
    unsigned int* bar) {
  __shared__ unsigned short wSh[2 * 16 * 520];          // 33280 B
  __shared__ float gS[1056];                            // 32 rows x 33
  __shared__ __align__(16) unsigned short hStage[256];
  const int tid = threadIdx.x, lane = tid & 63, wave = tid >> 6;
  const int bx = blockIdx.x;
  const int fm = lane & 15, fq = lane >> 4;

  if (bx < 64) {
    // ----------------------------- layer 0 --------------------------------
    const int j0 = bx * 8;
    {
      const int row = tid >> 3, cb = (tid & 7) * 64;   // row = g*8 + jl
      const unsigned short* wsrc =
          whh0 + ((long)((row >> 3) * 512 + j0 + (row & 7))) * 512 + cb;
      unsigned short* dst = wSh + row * 520 + cb;
#pragma unroll
      for (int c = 0; c < 64; c += 8) *(bf16x8*)(dst + c) = *(const bf16x8*)(wsrc + c);
    }
    __syncthreads();
    const int wm = wave & 1, wn = wave >> 1;
    const unsigned short* wrow = wSh + (wn * 16 + fm) * 520 + fq * 8;
    const long ab = wm * 16 + fm;
    const int cb2 = tid >> 3, jl = tid & 7;
    const float* xpp = xp + (long)cb2 * 513 * 2048 + j0 + jl;
    float cSt = 0.f;
#pragma unroll 1
    for (int t = 0; t < 513; ++t) {
      // xp loads issue before the poll -> HBM latency hides under the spin
      const float* xq = xpp + (long)t * 2048;
      float x0 = xq[0], x1 = xq[512], x2 = xq[1024], x3 = xq[1536];
      if (t > 0) {
        if (wave == 0) {
          int mn;
          do {
            int v = (int)ld_flag(bar + lane * 16);     // L0 flags 0..63
#pragma unroll
            for (int o = 32; o; o >>= 1) { int u = __shfl_xor(v, o); v = u < v ? u : v; }
            mn = v;
            if (mn < t) __builtin_amdgcn_s_sleep(1);
          } while (mn < t);
        }
        __syncthreads();
      }
      f32x4 acc = {0.f, 0.f, 0.f, 0.f};
      if (t > 0) {
        U128 afr[16];
        const unsigned short* hr = h0 + (ab * 513 + (t - 1)) * 512 + fq * 8;
#pragma unroll
        for (int kk = 0; kk < 16; ++kk) {
          afr[kk].q[0] = ld_dev(hr + kk * 32);
          afr[kk].q[1] = ld_dev(hr + kk * 32 + 4);
        }
#pragma unroll
        for (int kk = 0; kk < 16; ++kk)
          acc = __builtin_amdgcn_mfma_f32_16x16x32_bf16(
              afr[kk].v, *(const bf16x8*)(wrow + kk * 32), acc, 0, 0, 0);
      }
#pragma unroll
      for (int rr = 0; rr < 4; ++rr)
        gS[(wn * 16 + fm) * 33 + wm * 16 + fq * 4 + rr] = acc[rr];
      __syncthreads();
      {
        float gi = gS[jl * 33 + cb2] + x0;
        float gf = gS[(8 + jl) * 33 + cb2] + x1;
        float gg = gS[(16 + jl) * 33 + cb2] + x2;
        float go = gS[(24 + jl) * 33 + cb2] + x3;
        float ig = 1.f / (1.f + __expf(-gi));
        float fg = 1.f / (1.f + __expf(-gf));
        float og = 1.f / (1.f + __expf(-go));
        cSt = fg * cSt + ig * tanhf(gg);
        hStage[tid] = f2bf(og * tanhf(cSt));
      }
      __syncthreads();
      if (tid < 64) {
        const int b2 = tid >> 1, half = tid & 1;
        unsigned long long q = *(const unsigned long long*)(hStage + b2 * 8 + half * 4);
        st_dev(h0 + ((long)b2 * 513 + t) * 512 + j0 + half * 4, q);
      }
      __syncthreads();   // drains vmcnt(0): h stores at coherence point
      if (tid == 0) st_flag(bar + bx * 16, (unsigned int)(t + 1));
    }
  } else {
    // ----------------------------- layer 1 --------------------------------
    const int j0 = (bx - 64) * 4;
    {
      // 2 matrices x 16 rows (row = g*4 + jl) x 512
      const int mat = tid >> 7, row = (tid >> 3) & 15, cb = (tid & 7) * 64;
      const unsigned short* wsrc = (mat ? whh1 : wih1) +
          ((long)((row >> 2) * 512 + j0 + (row & 3))) * 512 + cb;
      unsigned short* dst = wSh + (mat * 16 + row) * 520 + cb;
#pragma unroll
      for (int c = 0; c < 64; c += 8) *(bf16x8*)(dst + c) = *(const bf16x8*)(wsrc + c);
    }
    __syncthreads();
    const int wm = wave & 1, ws = wave >> 1;   // ws: 0 = ih(h0[t]), 1 = hh(h1[t-1])
    const unsigned short* wrow = wSh + (ws * 16 + fm) * 520 + fq * 8;
    const long ab = wm * 16 + fm;
    const int cb2 = tid >> 2, jl = tid & 3;
    float bv0 = 0.f, bv1 = 0.f, bv2 = 0.f, bv3 = 0.f;
    if (tid < 128) {
      bv0 = bias1[j0 + jl];
      bv1 = bias1[512 + j0 + jl];
      bv2 = bias1[1024 + j0 + jl];
      bv3 = bias1[1536 + j0 + jl];
    }
    float cSt = 0.f;
#pragma unroll 1
    for (int t = 0; t < 513; ++t) {
      if (wave == 0) {
        int mn;
        do {
          int v0 = (int)ld_flag(bar + lane * 16);          // L0 flags
          int v1 = (int)ld_flag(bar + (64 + lane) * 16);   // L1 flags 0..63
          int v2 = (int)ld_flag(bar + (128 + lane) * 16);  // L1 flags 64..127
          int v = (v1 < v2 ? v1 : v2) + 1;                 // L1 threshold is t
          v = v0 < v ? v0 : v;                             // L0 threshold is t+1
#pragma unroll
          for (int o = 32; o; o >>= 1) { int u = __shfl_xor(v, o); v = u < v ? u : v; }
          mn = v;
          if (mn < t + 1) __builtin_amdgcn_s_sleep(1);
        } while (mn < t + 1);
      }
      __syncthreads();
      f32x4 acc = {0.f, 0.f, 0.f, 0.f};
      if (ws == 0 || t > 0) {
        const unsigned short* hr = (ws == 0)
            ? h0 + (ab * 513 + t) * 512 + fq * 8
            : h1 + (ab * 513 + (t - 1)) * 1024 + fq * 8;
        U128 hf[16];
#pragma unroll
        for (int kk = 0; kk < 16; ++kk) {
          hf[kk].q[0] = ld_dev(hr + kk * 32);
          hf[kk].q[1] = ld_dev(hr + kk * 32 + 4);
        }
#pragma unroll
        for (int kk = 0; kk < 16; ++kk)
          acc = __builtin_amdgcn_mfma_f32_16x16x32_bf16(
              hf[kk].v, *(const bf16x8*)(wrow + kk * 32), acc, 0, 0, 0);
      }
#pragma unroll
      for (int rr = 0; rr < 4; ++rr)
        gS[(ws * 16 + fm) * 33 + wm * 16 + fq * 4 + rr] = acc[rr];
      __syncthreads();
      if (tid < 128) {
        float gi = gS[jl * 33 + cb2]        + gS[(16 + jl) * 33 + cb2] + bv0;
        float gf = gS[(4 + jl) * 33 + cb2]  + gS[(20 + jl) * 33 + cb2] + bv1;
        float gg = gS[(8 + jl) * 33 + cb2]  + gS[(24 + jl) * 33 + cb2] + bv2;
        float go = gS[(12 + jl) * 33 + cb2] + gS[(28 + jl) * 33 + cb2] + bv3;
        float ig = 1.f / (1.f + __expf(-gi));
        float fg = 1.f / (1.f + __expf(-gf));
        float og = 1.f / (1.f + __expf(-go));
        cSt = fg * cSt + ig * tanhf(gg);
        hStage[tid] = f2bf(og * tanhf(cSt));
      }
      __syncthreads();
      if (tid < 32) {
        unsigned long long q = *(const unsigned long long*)(hStage + tid * 4);
        st_dev(h1 + ((long)tid * 513 + t) * 1024 + j0, q);
      }
      __syncthreads();   // drains h1 stores
      if (tid == 0) st_flag(bar + bx * 16, (unsigned int)(t + 1));
    }
  }
}

// --------------------------- small kernels ---------------------------------

struct CastJob { const float* src; unsigned short* dst; long n; };
struct CastJobs { CastJob j[11]; };
__global__ void cast_multi(CastJobs jb) {
  const CastJob j = jb.j[blockIdx.z];
  long n4 = j.n >> 2;
  for (long i = blockIdx.x * (long)blockDim.x + threadIdx.x; i < n4;
       i += (long)gridDim.x * blockDim.x) {
    float4 f = ((const float4*)j.src)[i];
    ushort4 o;
    o.x = f2bf(f.x); o.y = f2bf(f.y); o.z = f2bf(f.z); o.w = f2bf(f.w);
    ((ushort4*)j.dst)[i] = o;
  }
}

__global__ void bias_sum(const float* a0, const float* b0, float* o0,
                         const float* a1, const float* b1, float* o1) {
  int i = blockIdx.x * 256 + threadIdx.x;
  if (i < 2048) { o0[i] = a0[i] + b0[i]; o1[i] = a1[i] + b1[i]; }
}

__global__ __launch_bounds__(256) void embed_gather(const int* __restrict__ tg,
                                                    const unsigned short* __restrict__ emb,
                                                    unsigned short* __restrict__ out) {
  long row = blockIdx.x;                // 0..16415 = b*513+t
  int id = tg[row];
  const unsigned short* s = emb + (long)id * 512;
  unsigned short* d = out + row * 512;
  int c = threadIdx.x * 2;
  *(ushort2*)(d + c) = *(const ushort2*)(s + c);
}

__global__ void word_map(const int* __restrict__ tg, int* __restrict__ map) {
  int b = threadIdx.x;
  if (b >= 32) return;
  int word_id = 0, start = 0;
  for (int i = 0; i < 512; ++i) {
    int id = tg[b * 513 + i + 1];
    bool bd = (id == 1) || (id == 0);   // SPACE or PAD
    if (bd) {
      map[b * 512 + i] = -1;
      word_id++; start = i + 1;
    } else {
      int pos = i - start; if (pos > 6) pos = 6;
      map[b * 512 + i] = (b * 64 + word_id) * 7 + pos;
    }
  }
}

__global__ __launch_bounds__(256) void vtrans(const unsigned short* __restrict__ v,
                                              unsigned short* __restrict__ vt) {
  __shared__ unsigned short tile[64][33];
  const int bh = blockIdx.z, b = bh >> 2, h = bh & 3;
  const int s0 = blockIdx.x * 64, d0 = blockIdx.y * 32;
  const int tid = threadIdx.x;
  {
    const int dd = tid & 31, sb = tid >> 5;
#pragma unroll
    for (int k = 0; k < 8; ++k) {
      int s = sb + k * 8;
      tile[s][dd] = v[((long)b * 1024 + s0 + s) * 512 + h * 128 + d0 + dd];
    }
  }
  __syncthreads();
  {
    const int ss = tid & 63, db = tid >> 6;
#pragma unroll
    for (int k = 0; k < 8; ++k) {
      int d = db + k * 4;
      vt[((long)bh * 128 + d0 + d) * 1024 + s0 + ss] = tile[ss][d];
    }
  }
}

__global__ __launch_bounds__(256) void softmax_row(unsigned short* __restrict__ sc,
                                                   float* __restrict__ attnOut) {
  const long row = blockIdx.x;          // (b*4+h)*513 + t
  unsigned short* sr = sc + row * 1024;
  const int tid = threadIdx.x, lane = tid & 63, wave = tid >> 6;
  __shared__ float red[8];
  ushort4 raw = *(const ushort4*)(sr + tid * 4);
  float v0 = bf2f(raw.x), v1 = bf2f(raw.y), v2 = bf2f(raw.z), v3 = bf2f(raw.w);
  float m = fmaxf(fmaxf(v0, v1), fmaxf(v2, v3));
  for (int o = 32; o; o >>= 1) m = fmaxf(m, __shfl_down(m, o));
  if (lane == 0) red[wave] = m;
  __syncthreads();
  m = fmaxf(fmaxf(red[0], red[1]), fmaxf(red[2], red[3]));
  float e0 = __expf(v0 - m), e1 = __expf(v1 - m), e2 = __expf(v2 - m), e3 = __expf(v3 - m);
  float s = e0 + e1 + e2 + e3;
  for (int o = 32; o; o >>= 1) s += __shfl_down(s, o);
  if (lane == 0) red[4 + wave] = s;
  __syncthreads();
  float inv = 1.f / (red[4] + red[5] + red[6] + red[7]);
  float a0 = e0 * inv, a1 = e1 * inv, a2 = e2 * inv, a3 = e3 * inv;
  float4 fo; fo.x = a0; fo.y = a1; fo.z = a2; fo.w = a3;
  *(float4*)(attnOut + row * 1024 + tid * 4) = fo;
  ushort4 ob; ob.x = f2bf(a0); ob.y = f2bf(a1); ob.z = f2bf(a2); ob.w = f2bf(a3);
  *(ushort4*)(sr + tid * 4) = ob;       // in-place bf16 attn for ctx GEMM
}

__global__ __launch_bounds__(128) void mis_scatter(const int* __restrict__ map,
                                                   const int* __restrict__ tg,
                                                   const float* __restrict__ emb_w,
                                                   const float* __restrict__ ctx,
                                                   float* __restrict__ mis) {
  int bi = blockIdx.x;                  // b*512 + i
  int g = map[bi];
  if (g < 0) return;
  int b = bi >> 9, i = bi & 511;
  float* dst = mis + (long)g * 1024;
  int id = tg[b * 513 + i + 1];
  const float* es = emb_w + (long)id * 512;
  const float* cs = ctx + ((long)b * 513 + i) * 512;
  for (int c = threadIdx.x; c < 512; c += 128) {
    dst[c] = es[c];
    dst[512 + c] = cs[c];
  }
}

__global__ __launch_bounds__(256) void logsoftmax_rows(const float* __restrict__ logits,
                                                       float* __restrict__ out) {
  int row = blockIdx.x * 4 + (threadIdx.x >> 6);
  if (row >= 16416) return;
  int lane = threadIdx.x & 63;
  const float* lr = logits + (long)row * 128;
  float a = lr[lane], b = lr[lane + 64];
  float m = fmaxf(a, b);
  for (int o = 32; o; o >>= 1) m = fmaxf(m, __shfl_down(m, o));
  m = __shfl(m, 0);
  float s = __expf(a - m) + __expf(b - m);
  for (int o = 32; o; o >>= 1) s += __shfl_down(s, o);
  s = __shfl(s, 0);
  float ls = m + __logf(s);
  out[(long)row * 128 + lane] = a - ls;
  out[(long)row * 128 + lane + 64] = b - ls;
}

// ---------------------------------------------------------------------------

extern "C" void kernel_launch(void* const* d_in, const int* in_sizes, int n_in,
                              void* d_out, int out_size, void* d_ws, size_t ws_size,
                              hipStream_t stream) {
  (void)in_sizes; (void)n_in; (void)out_size; (void)ws_size;
  const int*   targets = (const int*)d_in[0];
  const float* enc   = (const float*)d_in[1];
  const float* emb_w = (const float*)d_in[2];
  const float* w_ih0 = (const float*)d_in[3];
  const float* w_hh0 = (const float*)d_in[4];
  const float* b_ih0 = (const float*)d_in[5];
  const float* b_hh0 = (const float*)d_in[6];
  const float* w_ih1 = (const float*)d_in[7];
  const float* w_hh1 = (const float*)d_in[8];
  const float* b_ih1 = (const float*)d_in[9];
  const float* b_hh1 = (const float*)d_in[10];
  const float* q_w = (const float*)d_in[11]; const float* q_b = (const float*)d_in[12];
  const float* k_w = (const float*)d_in[13]; const float* k_b = (const float*)d_in[14];
  const float* v_w = (const float*)d_in[15]; const float* v_b = (const float*)d_in[16];
  const float* fc1_w = (const float*)d_in[17]; const float* fc1_b = (const float*)d_in[18];
  const float* fc2_w = (const float*)d_in[19]; const float* fc2_b = (const float*)d_in[20];

  float* out_logp = (float*)d_out;
  float* out_attn = out_logp + 2101248;          // (32,4,513,1024)
  float* out_mis  = out_logp + 69341184;         // (2048,7,1024)

  // workspace arena
  char* ws = (char*)d_ws;
  size_t off = 0;
  auto take = [&](size_t bytes) -> char* {
    char* p = ws + off; off += (bytes + 255) & ~(size_t)255; return p;
  };
  unsigned int* bar   = (unsigned int*)take(65536);   // 192 flags, 64B apart
  int* map            = (int*)take(65536);
  float* bias0        = (float*)take(8192);
  float* bias1        = (float*)take(8192);
  unsigned short* wih0b = (unsigned short*)take(2097152);
  unsigned short* whh0b = (unsigned short*)take(2097152);
  unsigned short* wih1b = (unsigned short*)take(2097152);
  unsigned short* whh1b = (unsigned short*)take(2097152);
  unsigned short* qwb   = (unsigned short*)take(524288);
  unsigned short* kwb   = (unsigned short*)take(524288);
  unsigned short* vwb   = (unsigned short*)take(524288);
  unsigned short* fc1wb = (unsigned short*)take(1048576);
  unsigned short* fc2wb = (unsigned short*)take(131072);
  unsigned short* embb  = (unsigned short*)take(131072);
  unsigned short* emb_bf = (unsigned short*)take(16908288);  // (16512x512) bf16
  unsigned short* enc_bf = (unsigned short*)take(33554432);  // (32768x512)
  float* xp             = (float*)take(135266304);           // (16512x2048) f32; aliased by scores
  unsigned short* scores = (unsigned short*)xp;              // (128,513,1024) bf16 alias
  unsigned short* h0_bf = (unsigned short*)take(16908288);   // (16512x512)
  unsigned short* cat_bf = (unsigned short*)take(33816576);  // (16512x1024): [h1 | ctx]
  unsigned short* q_bf  = (unsigned short*)take(16908288);
  unsigned short* k_bf  = (unsigned short*)take(33554432);
  unsigned short* v_bf  = (unsigned short*)take(33554432);
  unsigned short* v_t   = (unsigned short*)take(33554432);   // (128,128,1024)
  float* ctx            = (float*)take(33816576);            // (16512x512)
  unsigned short* h1_bf = (unsigned short*)take(16908288);
  float* logits         = (float*)take(8454144);             // (16512x128)

  hipMemsetAsync(bar, 0, 32768, stream);
  hipMemsetAsync(out_mis, 0, (size_t)14680064 * 4, stream);

  // weight casts
  CastJobs cj;
  cj.j[0]  = {w_ih0, wih0b, 1048576};
  cj.j[1]  = {w_hh0, whh0b, 1048576};
  cj.j[2]  = {w_ih1, wih1b, 1048576};
  cj.j[3]  = {w_hh1, whh1b, 1048576};
  cj.j[4]  = {q_w,   qwb,   262144};
  cj.j[5]  = {k_w,   kwb,   262144};
  cj.j[6]  = {v_w,   vwb,   262144};
  cj.j[7]  = {fc1_w, fc1wb, 524288};
  cj.j[8]  = {fc2_w, fc2wb, 65536};
  cj.j[9]  = {emb_w, embb,  65536};
  cj.j[10] = {enc,   enc_bf, 16777216};
  cast_multi<<<dim3(256, 1, 11), 256, 0, stream>>>(cj);
  bias_sum<<<8, 256, 0, stream>>>(b_ih0, b_hh0, bias0, b_ih1, b_hh1, bias1);
  word_map<<<1, 64, 0, stream>>>(targets, map);
  embed_gather<<<16416, 256, 0, stream>>>(targets, embb, emb_bf);

  auto launch_gemm = [&](const unsigned short* A, long lda, long zA, long zAh,
                         const unsigned short* W, long ldw, long zW, long zWh,
                         const float* bias, float* C1, long ldc1, long zC1, long zC1h,
                         unsigned short* C2, long ldc2, long zC2, long zC2h,
                         long M, long Mclamp, int N, int K, int heads, int Z,
                         float alpha, int act) {
    Gemm g;
    g.A = A; g.W = W; g.bias = bias; g.C1 = C1; g.C2 = C2;
    g.lda = lda; g.ldw = ldw; g.ldc1 = ldc1; g.ldc2 = ldc2;
    g.zA = zA; g.zAh = zAh; g.zW = zW; g.zWh = zWh;
    g.zC1 = zC1; g.zC1h = zC1h; g.zC2 = zC2; g.zC2h = zC2h;
    g.M = M; g.Mclamp = Mclamp; g.N = N; g.K = K; g.heads = heads;
    g.act = act; g.alpha = alpha;
    dim3 grid((unsigned)(N / 128), (unsigned)((M + 127) / 128), (unsigned)Z);
    gemm_bt<<<grid, 256, 0, stream>>>(g);
  };

  // xp0 = embedded @ w_ih0^T + (b_ih0 + b_hh0)
  launch_gemm(emb_bf, 512, 0, 0, wih0b, 512, 0, 0, bias0,
              xp, 2048, 0, 0, nullptr, 0, 0, 0,
              16512, 16511, 2048, 512, 1, 1, 1.f, 0);
  // fused 2-layer recurrence: h0 -> h0_bf, h1 -> cat_bf left half
  lstm_fused<<<192, 256, 0, stream>>>(xp, wih1b, whh0b, whh1b, bias1,
                                      h0_bf, cat_bf, bar);

  // q / k / v projections (bf16 outputs)
  launch_gemm(cat_bf, 1024, 0, 0, qwb, 512, 0, 0, q_b,
              nullptr, 0, 0, 0, q_bf, 512, 0, 0,
              16512, 16511, 512, 512, 1, 1, 1.f, 0);
  launch_gemm(enc_bf, 512, 0, 0, kwb, 512, 0, 0, k_b,
              nullptr, 0, 0, 0, k_bf, 512, 0, 0,
              32768, 32767, 512, 512, 1, 1, 1.f, 0);
  launch_gemm(enc_bf, 512, 0, 0, vwb, 512, 0, 0, v_b,
              nullptr, 0, 0, 0, v_bf, 512, 0, 0,
              32768, 32767, 512, 512, 1, 1, 1.f, 0);
  vtrans<<<dim3(16, 4, 128), 256, 0, stream>>>(v_bf, v_t);

  // scores[b,h,t,s] = (q . k) / sqrt(128)   (bf16, into xp alias)
  launch_gemm(q_bf, 512, 262656, 128, k_bf, 512, 524288, 128, nullptr,
              nullptr, 0, 0, 0, scores, 1024, 2101248, 525312,
              513, 512, 1024, 128, 4, 128, 0.08838834764831845f, 0);
  // softmax rows -> attn f32 out + bf16 in place
  softmax_row<<<65664, 256, 0, stream>>>(scores, out_attn);
  // ctx[b,t,h*128+d] = attn @ v   (f32 ctx + bf16 into cat_bf right half)
  launch_gemm(scores, 1024, 2101248, 525312, v_t, 1024, 524288, 131072, nullptr,
              ctx, 512, 262656, 128, cat_bf + 512, 1024, 525312, 128,
              513, 512, 128, 1024, 4, 128, 1.f, 0);
  // mis scatter (embedded f32 gather + ctx f32)
  mis_scatter<<<16384, 128, 0, stream>>>(map, targets, emb_w, ctx, out_mis);

  // fc1: tanh(cat @ fc1_w^T + b) -> bf16
  launch_gemm(cat_bf, 1024, 0, 0, fc1wb, 1024, 0, 0, fc1_b,
              nullptr, 0, 0, 0, h1_bf, 512, 0, 0,
              16512, 16511, 512, 1024, 1, 1, 1.f, 1);
  // fc2: logits f32
  launch_gemm(h1_bf, 512, 0, 0, fc2wb, 512, 0, 0, fc2_b,
              logits, 128, 0, 0, nullptr, 0, 0, 0,
              16512, 16511, 128, 512, 1, 1, 1.f, 0);
  // log_softmax -> d_out
  logsoftmax_rows<<<4104, 256, 0, stream>>>(logits, out_logp);
}